// Round 1
// baseline (6090.077 us; speedup 1.0000x reference)
//
#include <hip/hip_runtime.h>

#define BN_EPS 1e-5f

// Column swizzle for the W tile in LDS: c ^ (4*(c>>5)) keeps float4 blocks
// contiguous, is injective within a 128-float row, and turns the 4-way
// read conflict (16 lanes * stride-8-float4 over 32 banks) into a free
// 2-way pattern.
__device__ __forceinline__ int swz(int c) { return c ^ (((c >> 5) & 3) << 2); }

// C[M x 128] = op(A)[M x 128] @ W[128 x 128]
// op(a)[n,c] = XFORM ? relu(sc[c]*a[n,c] + sh[c]) : a[n,c]   (fused BN+ReLU)
template <bool XFORM>
__global__ __launch_bounds__(256) void gemm128(
    const float* __restrict__ A, const float* __restrict__ W,
    float* __restrict__ C, const float* __restrict__ sc,
    const float* __restrict__ sh, int M)
{
    __shared__ float Ws[128 * 128];  // 64 KiB
    const int tid = threadIdx.x;

    // cooperative W load, swizzled columns
    for (int i = tid; i < 128 * 32; i += 256) {
        const int k = i >> 5, q = i & 31;
        float4 v = ((const float4*)W)[i];
        *(float4*)&Ws[k * 128 + swz(q << 2)] = v;
    }
    __syncthreads();

    const int tcol = tid & 15;          // 16 col-groups of 8
    const int trow = tid >> 4;          // 16 row-groups of 4
    const int c0 = tcol << 3;
    const int r0 = blockIdx.x * 64 + (trow << 2);
    const int p0 = swz(c0);
    const int p1 = swz(c0 + 4);

    float acc[4][8];
#pragma unroll
    for (int i = 0; i < 4; ++i)
#pragma unroll
        for (int j = 0; j < 8; ++j) acc[i][j] = 0.f;

    bool val[4];
#pragma unroll
    for (int i = 0; i < 4; ++i) val[i] = (r0 + i) < M;

    for (int jc = 0; jc < 32; ++jc) {   // k in chunks of 4 (one float4)
        float4 a[4];
#pragma unroll
        for (int i = 0; i < 4; ++i)
            a[i] = val[i] ? ((const float4*)A)[(size_t)(r0 + i) * 32 + jc]
                          : make_float4(0.f, 0.f, 0.f, 0.f);
        if (XFORM) {
            const float4 s4 = ((const float4*)sc)[jc];
            const float4 t4 = ((const float4*)sh)[jc];
#pragma unroll
            for (int i = 0; i < 4; ++i) {
                a[i].x = fmaxf(fmaf(s4.x, a[i].x, t4.x), 0.f);
                a[i].y = fmaxf(fmaf(s4.y, a[i].y, t4.y), 0.f);
                a[i].z = fmaxf(fmaf(s4.z, a[i].z, t4.z), 0.f);
                a[i].w = fmaxf(fmaf(s4.w, a[i].w, t4.w), 0.f);
            }
        }
#pragma unroll
        for (int kk = 0; kk < 4; ++kk) {
            const int k = (jc << 2) + kk;
            const float4 w0 = *(const float4*)&Ws[k * 128 + p0];
            const float4 w1 = *(const float4*)&Ws[k * 128 + p1];
#pragma unroll
            for (int i = 0; i < 4; ++i) {
                const float av = ((const float*)&a[i])[kk];
                acc[i][0] = fmaf(av, w0.x, acc[i][0]);
                acc[i][1] = fmaf(av, w0.y, acc[i][1]);
                acc[i][2] = fmaf(av, w0.z, acc[i][2]);
                acc[i][3] = fmaf(av, w0.w, acc[i][3]);
                acc[i][4] = fmaf(av, w1.x, acc[i][4]);
                acc[i][5] = fmaf(av, w1.y, acc[i][5]);
                acc[i][6] = fmaf(av, w1.z, acc[i][6]);
                acc[i][7] = fmaf(av, w1.w, acc[i][7]);
            }
        }
    }
#pragma unroll
    for (int i = 0; i < 4; ++i) {
        const int row = r0 + i;
        if (row < M) {
            float4 o0 = make_float4(acc[i][0], acc[i][1], acc[i][2], acc[i][3]);
            float4 o1 = make_float4(acc[i][4], acc[i][5], acc[i][6], acc[i][7]);
            ((float4*)C)[(size_t)row * 32 + (c0 >> 2)] = o0;
            ((float4*)C)[(size_t)row * 32 + (c0 >> 2) + 1] = o1;
        }
    }
}

// agg[dst_e, :] += w_e * h[src_e, :]   (32 lanes per edge, float4 each)
__global__ __launch_bounds__(256) void scatter_edges(
    const int* __restrict__ src, const int* __restrict__ dst,
    const float* __restrict__ ew, const float* __restrict__ h,
    float* __restrict__ agg, int E)
{
    const int t = blockIdx.x * 256 + threadIdx.x;
    const int e = t >> 5;
    if (e >= E) return;
    const int q = t & 31;
    const int s = src[e], d = dst[e];
    const float w = ew[e];
    const float4 v = ((const float4*)h)[(size_t)s * 32 + q];
    float* o = agg + (size_t)d * 128 + (q << 2);
    atomicAdd(o + 0, w * v.x);
    atomicAdd(o + 1, w * v.y);
    atomicAdd(o + 2, w * v.z);
    atomicAdd(o + 3, w * v.w);
}

// c[n] = sum of edge weights whose src == n
__global__ __launch_bounds__(256) void edge_csum(
    const int* __restrict__ src, const float* __restrict__ ew,
    float* __restrict__ cw, int E)
{
    const int e = blockIdx.x * 256 + threadIdx.x;
    if (e < E) atomicAdd(&cw[src[e]], ew[e]);
}

// per-column sum and sum-of-squares over rows of x[N,128]
__global__ __launch_bounds__(256) void bn_stats(
    const float* __restrict__ x, float* __restrict__ sum,
    float* __restrict__ sumsq, int N)
{
    __shared__ float4 ls[256], lq[256];
    const int tid = threadIdx.x;
    const int c4 = tid & 31, rr = tid >> 5;
    float4 s = {0, 0, 0, 0}, q = {0, 0, 0, 0};
    for (int row = blockIdx.x * 8 + rr; row < N; row += gridDim.x * 8) {
        const float4 v = ((const float4*)x)[(size_t)row * 32 + c4];
        s.x += v.x; s.y += v.y; s.z += v.z; s.w += v.w;
        q.x += v.x * v.x; q.y += v.y * v.y; q.z += v.z * v.z; q.w += v.w * v.w;
    }
    ls[tid] = s; lq[tid] = q;
    __syncthreads();
    for (int st = 128; st >= 32; st >>= 1) {
        if (tid < st) {
            ls[tid].x += ls[tid + st].x; ls[tid].y += ls[tid + st].y;
            ls[tid].z += ls[tid + st].z; ls[tid].w += ls[tid + st].w;
            lq[tid].x += lq[tid + st].x; lq[tid].y += lq[tid + st].y;
            lq[tid].z += lq[tid + st].z; lq[tid].w += lq[tid + st].w;
        }
        __syncthreads();
    }
    if (tid < 32) {
        const float4 fs = ls[tid], fq = lq[tid];
        atomicAdd(&sum[tid * 4 + 0], fs.x);
        atomicAdd(&sum[tid * 4 + 1], fs.y);
        atomicAdd(&sum[tid * 4 + 2], fs.z);
        atomicAdd(&sum[tid * 4 + 3], fs.w);
        atomicAdd(&sumsq[tid * 4 + 0], fq.x);
        atomicAdd(&sumsq[tid * 4 + 1], fq.y);
        atomicAdd(&sumsq[tid * 4 + 2], fq.z);
        atomicAdd(&sumsq[tid * 4 + 3], fq.w);
    }
}

// stats -> per-column affine: xhat = Ax*agg + Bx  (bias b cancels in BN)
__global__ void bn_finalize(
    const float* __restrict__ sum, const float* __restrict__ sumsq,
    const float* __restrict__ gamma, const float* __restrict__ beta,
    float* __restrict__ Ax, float* __restrict__ Bx, int N)
{
    const int c = threadIdx.x;  // 128 threads
    const float invN = 1.0f / (float)N;
    const float m = sum[c] * invN;
    const float var = sumsq[c] * invN - m * m;
    const float rs = rsqrtf(var + BN_EPS);
    Ax[c] = gamma[c] * rs;
    Bx[c] = beta[c] - gamma[c] * m * rs;
}

// sout[f] = sum_n cw[n] * relu(A1[f]*x[n,f] + B1[f])   (fused BN+ReLU)
__global__ __launch_bounds__(256) void wcolsum(
    const float* __restrict__ x, const float* __restrict__ cw,
    const float* __restrict__ A1, const float* __restrict__ B1,
    float* __restrict__ sout, int N)
{
    __shared__ float4 ls[256];
    const int tid = threadIdx.x;
    const int c4 = tid & 31, rr = tid >> 5;
    const float4 sa = ((const float4*)A1)[c4];
    const float4 sb = ((const float4*)B1)[c4];
    float4 s = {0, 0, 0, 0};
    for (int row = blockIdx.x * 8 + rr; row < N; row += gridDim.x * 8) {
        float4 v = ((const float4*)x)[(size_t)row * 32 + c4];
        const float c = cw[row];
        v.x = fmaxf(fmaf(sa.x, v.x, sb.x), 0.f);
        v.y = fmaxf(fmaf(sa.y, v.y, sb.y), 0.f);
        v.z = fmaxf(fmaf(sa.z, v.z, sb.z), 0.f);
        v.w = fmaxf(fmaf(sa.w, v.w, sb.w), 0.f);
        s.x = fmaf(c, v.x, s.x); s.y = fmaf(c, v.y, s.y);
        s.z = fmaf(c, v.z, s.z); s.w = fmaf(c, v.w, s.w);
    }
    ls[tid] = s;
    __syncthreads();
    for (int st = 128; st >= 32; st >>= 1) {
        if (tid < st) {
            ls[tid].x += ls[tid + st].x; ls[tid].y += ls[tid + st].y;
            ls[tid].z += ls[tid + st].z; ls[tid].w += ls[tid + st].w;
        }
        __syncthreads();
    }
    if (tid < 32) {
        const float4 fs = ls[tid];
        atomicAdd(&sout[tid * 4 + 0], fs.x);
        atomicAdd(&sout[tid * 4 + 1], fs.y);
        atomicAdd(&sout[tid * 4 + 2], fs.z);
        atomicAdd(&sout[tid * 4 + 3], fs.w);
    }
}

// out[j] = sum_f s[f] * W2[f, j] + N * b2[j]
__global__ void final_out(
    const float* __restrict__ s, const float* __restrict__ W2,
    const float* __restrict__ b2, float* __restrict__ out, int N, int Dout)
{
    const int j = threadIdx.x;
    if (j < Dout) {
        float acc = 0.f;
        for (int f = 0; f < 128; ++f) acc = fmaf(s[f], W2[f * Dout + j], acc);
        out[j] = acc + (float)N * b2[j];
    }
}

extern "C" void kernel_launch(void* const* d_in, const int* in_sizes, int n_in,
                              void* d_out, int out_size, void* d_ws, size_t ws_size,
                              hipStream_t stream)
{
    const float* nf  = (const float*)d_in[0];
    const int*   ei  = (const int*)d_in[1];
    const float* ew  = (const float*)d_in[2];
    const float* W0  = (const float*)d_in[3];
    // b0 = d_in[4], b1 = d_in[6]: cancel inside BatchNorm, unused
    const float* W1  = (const float*)d_in[5];
    const float* W2  = (const float*)d_in[7];
    const float* b2  = (const float*)d_in[8];
    const float* g0  = (const float*)d_in[9];
    const float* be0 = (const float*)d_in[10];
    const float* g1  = (const float*)d_in[11];
    const float* be1 = (const float*)d_in[12];

    const int N = in_sizes[0] / 128;
    const int E = in_sizes[2];
    const int* srcI = ei;       // edge_index[0,:]
    const int* dstI = ei + E;   // edge_index[1,:]

    const size_t NB = (size_t)N * 128 * sizeof(float);
    char* ws = (char*)d_ws;
    float* bufA = (float*)ws;                 // h0, then h1
    float* bufB = (float*)(ws + NB);          // agg0, then agg1
    float* cw   = (float*)(ws + 2 * NB);      // [N] src-weight sums
    const size_t cwBytes = ((size_t)N * sizeof(float) + 255) & ~(size_t)255;
    float* stats = (float*)(ws + 2 * NB + cwBytes);
    float* sum0 = stats + 0;   float* sq0  = stats + 128;
    float* sum1 = stats + 256; float* sq1  = stats + 384;
    float* A0   = stats + 512; float* B0v  = stats + 640;
    float* A1   = stats + 768; float* B1v  = stats + 896;
    float* svec = stats + 1024;               // [128]

    const int gemmGrid    = (N + 63) / 64;
    const int scatterGrid = (E * 32 + 255) / 256;
    const int redGrid     = 1024;

    // zero the accumulation targets (ws is re-poisoned 0xAA before each launch)
    hipMemsetAsync(bufB, 0, NB, stream);
    hipMemsetAsync(cw, 0, (size_t)N * sizeof(float), stream);
    hipMemsetAsync(stats, 0, 1280 * sizeof(float), stream);

    // per-src weight sums for the collapsed final layer (independent of layers 0/1)
    edge_csum<<<(E + 255) / 256, 256, 0, stream>>>(srcI, ew, cw, E);

    // ---- layer 0 ----
    gemm128<false><<<gemmGrid, 256, 0, stream>>>(nf, W0, bufA, nullptr, nullptr, N);
    scatter_edges<<<scatterGrid, 256, 0, stream>>>(srcI, dstI, ew, bufA, bufB, E);
    bn_stats<<<redGrid, 256, 0, stream>>>(bufB, sum0, sq0, N);
    bn_finalize<<<1, 128, 0, stream>>>(sum0, sq0, g0, be0, A0, B0v, N);

    // ---- layer 1 (BN+ReLU of layer 0 fused into the A-load) ----
    gemm128<true><<<gemmGrid, 256, 0, stream>>>(bufB, W1, bufA, A0, B0v, N);
    hipMemsetAsync(bufB, 0, NB, stream);
    scatter_edges<<<scatterGrid, 256, 0, stream>>>(srcI, dstI, ew, bufA, bufB, E);
    bn_stats<<<redGrid, 256, 0, stream>>>(bufB, sum1, sq1, N);
    bn_finalize<<<1, 128, 0, stream>>>(sum1, sq1, g1, be1, A1, B1v, N);

    // ---- collapsed layer 2: out = (sum_n cw[n]*x2[n,:]) @ W2 + N*b2 ----
    wcolsum<<<redGrid, 256, 0, stream>>>(bufB, cw, A1, B1v, svec, N);
    final_out<<<1, 64, 0, stream>>>(svec, W2, b2, (float*)d_out, N, out_size);
}

// Round 2
// 1238.536 us; speedup vs baseline: 4.9172x; 4.9172x over previous
//
#include <hip/hip_runtime.h>

#define BN_EPS 1e-5f

// Column swizzle for the W tile in LDS: c ^ (4*(c>>5)) keeps float4 blocks
// contiguous, is injective within a 128-float row, and turns the 4-way
// read conflict into a free 2-way pattern.
__device__ __forceinline__ int swz(int c) { return c ^ (((c >> 5) & 3) << 2); }

// C[M x 128] = op(A)[M x 128] @ W[128 x 128]
// op(a)[n,c] = XFORM ? relu(sc[c]*a[n,c] + sh[c]) : a[n,c]   (fused BN+ReLU)
template <bool XFORM>
__global__ __launch_bounds__(256) void gemm128(
    const float* __restrict__ A, const float* __restrict__ W,
    float* __restrict__ C, const float* __restrict__ sc,
    const float* __restrict__ sh, int M)
{
    __shared__ float Ws[128 * 128];  // 64 KiB
    const int tid = threadIdx.x;

    for (int i = tid; i < 128 * 32; i += 256) {
        const int k = i >> 5, q = i & 31;
        float4 v = ((const float4*)W)[i];
        *(float4*)&Ws[k * 128 + swz(q << 2)] = v;
    }
    __syncthreads();

    const int tcol = tid & 15;
    const int trow = tid >> 4;
    const int c0 = tcol << 3;
    const int r0 = blockIdx.x * 64 + (trow << 2);
    const int p0 = swz(c0);
    const int p1 = swz(c0 + 4);

    float acc[4][8];
#pragma unroll
    for (int i = 0; i < 4; ++i)
#pragma unroll
        for (int j = 0; j < 8; ++j) acc[i][j] = 0.f;

    bool val[4];
#pragma unroll
    for (int i = 0; i < 4; ++i) val[i] = (r0 + i) < M;

    for (int jc = 0; jc < 32; ++jc) {
        float4 a[4];
#pragma unroll
        for (int i = 0; i < 4; ++i)
            a[i] = val[i] ? ((const float4*)A)[(size_t)(r0 + i) * 32 + jc]
                          : make_float4(0.f, 0.f, 0.f, 0.f);
        if (XFORM) {
            const float4 s4 = ((const float4*)sc)[jc];
            const float4 t4 = ((const float4*)sh)[jc];
#pragma unroll
            for (int i = 0; i < 4; ++i) {
                a[i].x = fmaxf(fmaf(s4.x, a[i].x, t4.x), 0.f);
                a[i].y = fmaxf(fmaf(s4.y, a[i].y, t4.y), 0.f);
                a[i].z = fmaxf(fmaf(s4.z, a[i].z, t4.z), 0.f);
                a[i].w = fmaxf(fmaf(s4.w, a[i].w, t4.w), 0.f);
            }
        }
#pragma unroll
        for (int kk = 0; kk < 4; ++kk) {
            const int k = (jc << 2) + kk;
            const float4 w0 = *(const float4*)&Ws[k * 128 + p0];
            const float4 w1 = *(const float4*)&Ws[k * 128 + p1];
#pragma unroll
            for (int i = 0; i < 4; ++i) {
                const float av = ((const float*)&a[i])[kk];
                acc[i][0] = fmaf(av, w0.x, acc[i][0]);
                acc[i][1] = fmaf(av, w0.y, acc[i][1]);
                acc[i][2] = fmaf(av, w0.z, acc[i][2]);
                acc[i][3] = fmaf(av, w0.w, acc[i][3]);
                acc[i][4] = fmaf(av, w1.x, acc[i][4]);
                acc[i][5] = fmaf(av, w1.y, acc[i][5]);
                acc[i][6] = fmaf(av, w1.z, acc[i][6]);
                acc[i][7] = fmaf(av, w1.w, acc[i][7]);
            }
        }
    }
#pragma unroll
    for (int i = 0; i < 4; ++i) {
        const int row = r0 + i;
        if (row < M) {
            float4 o0 = make_float4(acc[i][0], acc[i][1], acc[i][2], acc[i][3]);
            float4 o1 = make_float4(acc[i][4], acc[i][5], acc[i][6], acc[i][7]);
            ((float4*)C)[(size_t)row * 32 + (c0 >> 2)] = o0;
            ((float4*)C)[(size_t)row * 32 + (c0 >> 2) + 1] = o1;
        }
    }
}

// ---------------- CSR build (counting sort by dst) ----------------

// cnt[dst]++ and cw[src] += w in one pass over edges
__global__ __launch_bounds__(256) void hist(
    const int* __restrict__ src, const int* __restrict__ dst,
    const float* __restrict__ ew, int* __restrict__ cnt,
    float* __restrict__ cw, int E)
{
    const int e = blockIdx.x * 256 + threadIdx.x;
    if (e < E) {
        atomicAdd(&cnt[dst[e]], 1);
        atomicAdd(&cw[src[e]], ew[e]);
    }
}

// per-1024-chunk sums
__global__ __launch_bounds__(256) void scan1(
    const int* __restrict__ cnt, int* __restrict__ bsum, int N)
{
    __shared__ int ls[256];
    const int base = blockIdx.x * 1024;
    const int tid = threadIdx.x;
    int s = 0;
#pragma unroll
    for (int i = 0; i < 4; ++i) {
        const int idx = base + tid * 4 + i;
        if (idx < N) s += cnt[idx];
    }
    ls[tid] = s;
    __syncthreads();
    for (int st = 128; st >= 1; st >>= 1) {
        if (tid < st) ls[tid] += ls[tid + st];
        __syncthreads();
    }
    if (tid == 0) bsum[blockIdx.x] = ls[0];
}

// exclusive scan of chunk sums (nb <= 128), single block of 128
__global__ void scan2(int* __restrict__ bsum, int nb)
{
    __shared__ int ls[128];
    const int tid = threadIdx.x;
    const int v = (tid < nb) ? bsum[tid] : 0;
    ls[tid] = v;
    __syncthreads();
    for (int st = 1; st < 128; st <<= 1) {
        const int t = (tid >= st) ? ls[tid - st] : 0;
        __syncthreads();
        ls[tid] += t;
        __syncthreads();
    }
    if (tid < nb) bsum[tid] = ls[tid] - v;  // exclusive
}

// exclusive prefix within chunk + chunk offset -> rp[n] = start_n
__global__ __launch_bounds__(256) void scan3(
    const int* __restrict__ cnt, const int* __restrict__ bsum,
    int* __restrict__ rp, int N)
{
    __shared__ int ls[256];
    const int base = blockIdx.x * 1024;
    const int tid = threadIdx.x;
    int c[4];
    int s = 0;
#pragma unroll
    for (int i = 0; i < 4; ++i) {
        const int idx = base + tid * 4 + i;
        c[i] = (idx < N) ? cnt[idx] : 0;
        s += c[i];
    }
    ls[tid] = s;
    __syncthreads();
    for (int st = 1; st < 256; st <<= 1) {
        const int v = (tid >= st) ? ls[tid - st] : 0;
        __syncthreads();
        ls[tid] += v;
        __syncthreads();
    }
    int excl = ls[tid] - s + bsum[blockIdx.x];
#pragma unroll
    for (int i = 0; i < 4; ++i) {
        const int idx = base + tid * 4 + i;
        if (idx < N) rp[idx] = excl;
        excl += c[i];
    }
}

// counting-sort placement; rp doubles as cursor (after this, rp[n] = end_n)
__global__ __launch_bounds__(256) void reorder(
    const int* __restrict__ src, const int* __restrict__ dst,
    const float* __restrict__ ew, int* __restrict__ rp,
    int2* __restrict__ packed, int E)
{
    const int e = blockIdx.x * 256 + threadIdx.x;
    if (e < E) {
        const int pos = atomicAdd(&rp[dst[e]], 1);
        packed[pos] = make_int2(src[e], __float_as_int(ew[e]));
    }
}

// atomic-free aggregation: one 64-lane wave per node, float2 per lane.
// agg[n,:] = sum_{e: dst==n} w_e * h[src_e,:]
__global__ __launch_bounds__(256) void aggregate(
    const int2* __restrict__ packed, const int* __restrict__ rp,
    const float* __restrict__ h, float* __restrict__ agg, int N)
{
    const int lane = threadIdx.x & 63;
    const int n = (blockIdx.x * 256 + threadIdx.x) >> 6;
    if (n >= N) return;
    const int start = (n == 0) ? 0 : rp[n - 1];
    const int end = rp[n];
    float2 acc = {0.f, 0.f};
    for (int k = start; k < end; ++k) {
        const int2 p = packed[k];
        const float w = __int_as_float(p.y);
        const float2 v = ((const float2*)h)[(size_t)p.x * 64 + lane];
        acc.x = fmaf(w, v.x, acc.x);
        acc.y = fmaf(w, v.y, acc.y);
    }
    ((float2*)agg)[(size_t)n * 64 + lane] = acc;
}

// ---------------- fallback atomic scatter (if ws too small) ----------------

__global__ __launch_bounds__(256) void scatter_edges(
    const int* __restrict__ src, const int* __restrict__ dst,
    const float* __restrict__ ew, const float* __restrict__ h,
    float* __restrict__ agg, int E)
{
    const int t = blockIdx.x * 256 + threadIdx.x;
    const int e = t >> 5;
    if (e >= E) return;
    const int q = t & 31;
    const int s = src[e], d = dst[e];
    const float w = ew[e];
    const float4 v = ((const float4*)h)[(size_t)s * 32 + q];
    float* o = agg + (size_t)d * 128 + (q << 2);
    atomicAdd(o + 0, w * v.x);
    atomicAdd(o + 1, w * v.y);
    atomicAdd(o + 2, w * v.z);
    atomicAdd(o + 3, w * v.w);
}

__global__ __launch_bounds__(256) void edge_csum(
    const int* __restrict__ src, const float* __restrict__ ew,
    float* __restrict__ cw, int E)
{
    const int e = blockIdx.x * 256 + threadIdx.x;
    if (e < E) atomicAdd(&cw[src[e]], ew[e]);
}

// ---------------- BN / epilogue ----------------

__global__ __launch_bounds__(256) void bn_stats(
    const float* __restrict__ x, float* __restrict__ sum,
    float* __restrict__ sumsq, int N)
{
    __shared__ float4 ls[256], lq[256];
    const int tid = threadIdx.x;
    const int c4 = tid & 31, rr = tid >> 5;
    float4 s = {0, 0, 0, 0}, q = {0, 0, 0, 0};
    for (int row = blockIdx.x * 8 + rr; row < N; row += gridDim.x * 8) {
        const float4 v = ((const float4*)x)[(size_t)row * 32 + c4];
        s.x += v.x; s.y += v.y; s.z += v.z; s.w += v.w;
        q.x += v.x * v.x; q.y += v.y * v.y; q.z += v.z * v.z; q.w += v.w * v.w;
    }
    ls[tid] = s; lq[tid] = q;
    __syncthreads();
    for (int st = 128; st >= 32; st >>= 1) {
        if (tid < st) {
            ls[tid].x += ls[tid + st].x; ls[tid].y += ls[tid + st].y;
            ls[tid].z += ls[tid + st].z; ls[tid].w += ls[tid + st].w;
            lq[tid].x += lq[tid + st].x; lq[tid].y += lq[tid + st].y;
            lq[tid].z += lq[tid + st].z; lq[tid].w += lq[tid + st].w;
        }
        __syncthreads();
    }
    if (tid < 32) {
        const float4 fs = ls[tid], fq = lq[tid];
        atomicAdd(&sum[tid * 4 + 0], fs.x);
        atomicAdd(&sum[tid * 4 + 1], fs.y);
        atomicAdd(&sum[tid * 4 + 2], fs.z);
        atomicAdd(&sum[tid * 4 + 3], fs.w);
        atomicAdd(&sumsq[tid * 4 + 0], fq.x);
        atomicAdd(&sumsq[tid * 4 + 1], fq.y);
        atomicAdd(&sumsq[tid * 4 + 2], fq.z);
        atomicAdd(&sumsq[tid * 4 + 3], fq.w);
    }
}

__global__ void bn_finalize(
    const float* __restrict__ sum, const float* __restrict__ sumsq,
    const float* __restrict__ gamma, const float* __restrict__ beta,
    float* __restrict__ Ax, float* __restrict__ Bx, int N)
{
    const int c = threadIdx.x;  // 128
    const float invN = 1.0f / (float)N;
    const float m = sum[c] * invN;
    const float var = sumsq[c] * invN - m * m;
    const float rs = rsqrtf(var + BN_EPS);
    Ax[c] = gamma[c] * rs;
    Bx[c] = beta[c] - gamma[c] * m * rs;
}

// sout[f] = sum_n cw[n] * relu(A1[f]*x[n,f] + B1[f])
__global__ __launch_bounds__(256) void wcolsum(
    const float* __restrict__ x, const float* __restrict__ cw,
    const float* __restrict__ A1, const float* __restrict__ B1,
    float* __restrict__ sout, int N)
{
    __shared__ float4 ls[256];
    const int tid = threadIdx.x;
    const int c4 = tid & 31, rr = tid >> 5;
    const float4 sa = ((const float4*)A1)[c4];
    const float4 sb = ((const float4*)B1)[c4];
    float4 s = {0, 0, 0, 0};
    for (int row = blockIdx.x * 8 + rr; row < N; row += gridDim.x * 8) {
        float4 v = ((const float4*)x)[(size_t)row * 32 + c4];
        const float c = cw[row];
        v.x = fmaxf(fmaf(sa.x, v.x, sb.x), 0.f);
        v.y = fmaxf(fmaf(sa.y, v.y, sb.y), 0.f);
        v.z = fmaxf(fmaf(sa.z, v.z, sb.z), 0.f);
        v.w = fmaxf(fmaf(sa.w, v.w, sb.w), 0.f);
        s.x = fmaf(c, v.x, s.x); s.y = fmaf(c, v.y, s.y);
        s.z = fmaf(c, v.z, s.z); s.w = fmaf(c, v.w, s.w);
    }
    ls[tid] = s;
    __syncthreads();
    for (int st = 128; st >= 32; st >>= 1) {
        if (tid < st) {
            ls[tid].x += ls[tid + st].x; ls[tid].y += ls[tid + st].y;
            ls[tid].z += ls[tid + st].z; ls[tid].w += ls[tid + st].w;
        }
        __syncthreads();
    }
    if (tid < 32) {
        const float4 fs = ls[tid];
        atomicAdd(&sout[tid * 4 + 0], fs.x);
        atomicAdd(&sout[tid * 4 + 1], fs.y);
        atomicAdd(&sout[tid * 4 + 2], fs.z);
        atomicAdd(&sout[tid * 4 + 3], fs.w);
    }
}

__global__ void final_out(
    const float* __restrict__ s, const float* __restrict__ W2,
    const float* __restrict__ b2, float* __restrict__ out, int N, int Dout)
{
    const int j = threadIdx.x;
    if (j < Dout) {
        float acc = 0.f;
        for (int f = 0; f < 128; ++f) acc = fmaf(s[f], W2[f * Dout + j], acc);
        out[j] = acc + (float)N * b2[j];
    }
}

extern "C" void kernel_launch(void* const* d_in, const int* in_sizes, int n_in,
                              void* d_out, int out_size, void* d_ws, size_t ws_size,
                              hipStream_t stream)
{
    const float* nf  = (const float*)d_in[0];
    const int*   ei  = (const int*)d_in[1];
    const float* ew  = (const float*)d_in[2];
    const float* W0  = (const float*)d_in[3];
    // b0 = d_in[4], b1 = d_in[6]: cancel inside BatchNorm, unused
    const float* W1  = (const float*)d_in[5];
    const float* W2  = (const float*)d_in[7];
    const float* b2  = (const float*)d_in[8];
    const float* g0  = (const float*)d_in[9];
    const float* be0 = (const float*)d_in[10];
    const float* g1  = (const float*)d_in[11];
    const float* be1 = (const float*)d_in[12];

    const int N = in_sizes[0] / 128;
    const int E = in_sizes[2];
    const int* srcI = ei;       // edge_index[0,:]
    const int* dstI = ei + E;   // edge_index[1,:]

    const size_t NB = (size_t)N * 128 * sizeof(float);
    const size_t NA = ((size_t)N * sizeof(int) + 255) & ~(size_t)255;
    char* ws = (char*)d_ws;
    size_t off = 0;
    float* bufA = (float*)(ws + off); off += NB;       // h0, then h1
    float* bufB = (float*)(ws + off); off += NB;       // agg0, then agg1
    float* cw   = (float*)(ws + off); off += NA;       // [N] src-weight sums
    int*   cnt  = (int*)  (ws + off); off += NA;       // [N] in-degree
    int*   rp   = (int*)  (ws + off); off += NA;       // [N] row ptr / cursor
    int*   bsum = (int*)  (ws + off); off += 512;      // [<=128] chunk sums
    float* stats= (float*)(ws + off); off += 8192;
    int2*  packed=(int2*) (ws + off); off += (size_t)E * 8;  // (src, w) by dst

    float* sum0 = stats + 0;   float* sq0  = stats + 128;
    float* sum1 = stats + 256; float* sq1  = stats + 384;
    float* A0   = stats + 512; float* B0v  = stats + 640;
    float* A1   = stats + 768; float* B1v  = stats + 896;
    float* svec = stats + 1024;               // [128]

    const int gemmGrid = (N + 63) / 64;
    const int edgeGrid = (E + 255) / 256;
    const int redGrid  = 1024;
    const int nChunks  = (N + 1023) / 1024;   // 98 <= 128
    const int aggGrid  = (N * 64 + 255) / 256;

    const bool csr = (off <= ws_size) && (nChunks <= 128);

    hipMemsetAsync(cw, 0, (size_t)N * sizeof(float), stream);
    hipMemsetAsync(stats, 0, 1280 * sizeof(float), stream);

    if (csr) {
        // ---- build dst-CSR once (graph identical both layers) ----
        hipMemsetAsync(cnt, 0, (size_t)N * sizeof(int), stream);
        hist<<<edgeGrid, 256, 0, stream>>>(srcI, dstI, ew, cnt, cw, E);
        scan1<<<nChunks, 256, 0, stream>>>(cnt, bsum, N);
        scan2<<<1, 128, 0, stream>>>(bsum, nChunks);
        scan3<<<nChunks, 256, 0, stream>>>(cnt, bsum, rp, N);
        reorder<<<edgeGrid, 256, 0, stream>>>(srcI, dstI, ew, rp, packed, E);

        // ---- layer 0 ----
        gemm128<false><<<gemmGrid, 256, 0, stream>>>(nf, W0, bufA, nullptr, nullptr, N);
        aggregate<<<aggGrid, 256, 0, stream>>>(packed, rp, bufA, bufB, N);
        bn_stats<<<redGrid, 256, 0, stream>>>(bufB, sum0, sq0, N);
        bn_finalize<<<1, 128, 0, stream>>>(sum0, sq0, g0, be0, A0, B0v, N);

        // ---- layer 1 (BN+ReLU fused into GEMM A-load) ----
        gemm128<true><<<gemmGrid, 256, 0, stream>>>(bufB, W1, bufA, A0, B0v, N);
        aggregate<<<aggGrid, 256, 0, stream>>>(packed, rp, bufA, bufB, N);
        bn_stats<<<redGrid, 256, 0, stream>>>(bufB, sum1, sq1, N);
        bn_finalize<<<1, 128, 0, stream>>>(sum1, sq1, g1, be1, A1, B1v, N);
    } else {
        // ---- fallback: proven atomic-scatter path ----
        const int scatterGrid = (E * 32 + 255) / 256;
        hipMemsetAsync(bufB, 0, NB, stream);
        edge_csum<<<edgeGrid, 256, 0, stream>>>(srcI, ew, cw, E);

        gemm128<false><<<gemmGrid, 256, 0, stream>>>(nf, W0, bufA, nullptr, nullptr, N);
        scatter_edges<<<scatterGrid, 256, 0, stream>>>(srcI, dstI, ew, bufA, bufB, E);
        bn_stats<<<redGrid, 256, 0, stream>>>(bufB, sum0, sq0, N);
        bn_finalize<<<1, 128, 0, stream>>>(sum0, sq0, g0, be0, A0, B0v, N);

        gemm128<true><<<gemmGrid, 256, 0, stream>>>(bufB, W1, bufA, A0, B0v, N);
        hipMemsetAsync(bufB, 0, NB, stream);
        scatter_edges<<<scatterGrid, 256, 0, stream>>>(srcI, dstI, ew, bufA, bufB, E);
        bn_stats<<<redGrid, 256, 0, stream>>>(bufB, sum1, sq1, N);
        bn_finalize<<<1, 128, 0, stream>>>(sum1, sq1, g1, be1, A1, B1v, N);
    }

    // ---- collapsed layer 2: out = (sum_n cw[n]*x2[n,:]) @ W2 + N*b2 ----
    wcolsum<<<redGrid, 256, 0, stream>>>(bufB, cw, A1, B1v, svec, N);
    final_out<<<1, 64, 0, stream>>>(svec, W2, b2, (float*)d_out, N, out_size);
}

// Round 3
// 1048.150 us; speedup vs baseline: 5.8103x; 1.1816x over previous
//
#include <hip/hip_runtime.h>

#define BN_EPS 1e-5f

typedef __attribute__((ext_vector_type(8))) short short8;
typedef __attribute__((ext_vector_type(4))) float floatx4;

__device__ __forceinline__ unsigned short f2bf(float f) {
    unsigned u = __float_as_uint(f);
    unsigned r = u + 0x7FFFu + ((u >> 16) & 1u);   // round-to-nearest-even
    return (unsigned short)(r >> 16);
}
__device__ __forceinline__ float bf2f(unsigned short h) {
    return __uint_as_float(((unsigned)h) << 16);
}

// ---------------- W pre-transpose: wt[n][k] = bf16(W[k][n]) ----------------
__global__ __launch_bounds__(256) void wconv(
    const float* __restrict__ W0, const float* __restrict__ W1,
    unsigned short* __restrict__ wt0, unsigned short* __restrict__ wt1)
{
    const int idx = blockIdx.x * 256 + threadIdx.x;   // < 16384
    const int n = idx >> 7, k = idx & 127;
    wt0[idx] = f2bf(W0[k * 128 + n]);
    wt1[idx] = f2bf(W1[k * 128 + n]);
}

// ---------------- bf16 MFMA GEMM: C[M x 128] = op(A) @ W ----------------
// op(a)[n,c] = XFORM ? relu(sc[c]*a[n,c] + sh[c]) : a[n,c]   (fused BN+ReLU)
// A fp32 [M][128], Wt bf16 [n][k] (pre-transposed), C bf16 [M][128].
// Block: 64 rows, 4 waves; wave owns 2 col-tiles x 4 row-tiles of 16x16.
// Frag layouts (m89/m120-verified): A[m=lane&15][k=(lane>>4)*8+j],
// B[k=(lane>>4)*8+j][n=lane&15], D: col=lane&15, row=(lane>>4)*4+reg.
template <bool XFORM>
__global__ __launch_bounds__(256) void gemm_mfma(
    const float* __restrict__ A, const unsigned short* __restrict__ Wt,
    unsigned short* __restrict__ C, const float* __restrict__ sc,
    const float* __restrict__ sh, int M)
{
    __shared__ char lds[52224];
    unsigned short* Al = (unsigned short*)lds;            // [64][136] bf16
    unsigned short* Wl = (unsigned short*)(lds + 17408);  // [128][136] bf16
    float* Cl = (float*)lds;                              // [64][132] f32 (reuse)

    const int tid = threadIdx.x;
    const int r0 = blockIdx.x * 64;

    // stage W^T (bf16, rows padded to 136 to break bank conflicts)
#pragma unroll
    for (int i = 0; i < 16; ++i) {
        const int idx = i * 256 + tid;          // ushort4 units
        const int n = idx >> 5, q = idx & 31;
        const ushort4 v = ((const ushort4*)Wt)[idx];
        *(ushort4*)&Wl[n * 136 + q * 4] = v;
    }
    // stage A tile (fp32 -> optional BN+ReLU -> bf16)
#pragma unroll
    for (int i = 0; i < 8; ++i) {
        const int row = i * 8 + (tid >> 5), q = tid & 31;
        const int gr = r0 + row;
        float4 v = (gr < M) ? ((const float4*)A)[(size_t)gr * 32 + q]
                            : make_float4(0.f, 0.f, 0.f, 0.f);
        if (XFORM) {
            const float4 s4 = ((const float4*)sc)[q];
            const float4 t4 = ((const float4*)sh)[q];
            v.x = fmaxf(fmaf(s4.x, v.x, t4.x), 0.f);
            v.y = fmaxf(fmaf(s4.y, v.y, t4.y), 0.f);
            v.z = fmaxf(fmaf(s4.z, v.z, t4.z), 0.f);
            v.w = fmaxf(fmaf(s4.w, v.w, t4.w), 0.f);
        }
        ushort4 o;
        o.x = f2bf(v.x); o.y = f2bf(v.y); o.z = f2bf(v.z); o.w = f2bf(v.w);
        *(ushort4*)&Al[row * 136 + q * 4] = o;
    }
    __syncthreads();

    const int wave = tid >> 6, lane = tid & 63;
    const int lrow = lane & 15, quad = lane >> 4;
    const int n0 = wave * 32;                   // this wave's 2 col-tiles

    floatx4 acc[4][2];
#pragma unroll
    for (int mt = 0; mt < 4; ++mt)
#pragma unroll
        for (int t = 0; t < 2; ++t)
#pragma unroll
            for (int j = 0; j < 4; ++j) acc[mt][t][j] = 0.f;

#pragma unroll
    for (int c = 0; c < 4; ++c) {
        const int k0 = c * 32;
        const short8 b0 = *(const short8*)&Wl[(n0 + lrow) * 136 + k0 + quad * 8];
        const short8 b1 = *(const short8*)&Wl[(n0 + 16 + lrow) * 136 + k0 + quad * 8];
#pragma unroll
        for (int mt = 0; mt < 4; ++mt) {
            const short8 a = *(const short8*)&Al[(mt * 16 + lrow) * 136 + k0 + quad * 8];
            acc[mt][0] = __builtin_amdgcn_mfma_f32_16x16x32_bf16(a, b0, acc[mt][0], 0, 0, 0);
            acc[mt][1] = __builtin_amdgcn_mfma_f32_16x16x32_bf16(a, b1, acc[mt][1], 0, 0, 0);
        }
    }
    __syncthreads();

    // D-layout -> LDS (fp32), then coalesced bf16 writeout
#pragma unroll
    for (int mt = 0; mt < 4; ++mt)
#pragma unroll
        for (int t = 0; t < 2; ++t)
#pragma unroll
            for (int j = 0; j < 4; ++j)
                Cl[(mt * 16 + quad * 4 + j) * 132 + n0 + t * 16 + lrow] = acc[mt][t][j];
    __syncthreads();

#pragma unroll
    for (int i = 0; i < 4; ++i) {
        const int row = i * 16 + (tid >> 4);
        const int c0 = (tid & 15) * 8;
        const int gr = r0 + row;
        if (gr < M) {
            const float4 v0 = *(float4*)&Cl[row * 132 + c0];
            const float4 v1 = *(float4*)&Cl[row * 132 + c0 + 4];
            uint4 o;
            o.x = (unsigned)f2bf(v0.x) | ((unsigned)f2bf(v0.y) << 16);
            o.y = (unsigned)f2bf(v0.z) | ((unsigned)f2bf(v0.w) << 16);
            o.z = (unsigned)f2bf(v1.x) | ((unsigned)f2bf(v1.y) << 16);
            o.w = (unsigned)f2bf(v1.z) | ((unsigned)f2bf(v1.w) << 16);
            ((uint4*)C)[(size_t)gr * 16 + (c0 >> 3)] = o;
        }
    }
}

// ---------------- CSR build (counting sort by dst) ----------------

__global__ __launch_bounds__(256) void hist(
    const int* __restrict__ src, const int* __restrict__ dst,
    const float* __restrict__ ew, int* __restrict__ cnt,
    float* __restrict__ cw, int E)
{
    const int e = blockIdx.x * 256 + threadIdx.x;
    if (e < E) {
        atomicAdd(&cnt[dst[e]], 1);
        atomicAdd(&cw[src[e]], ew[e]);
    }
}

__global__ __launch_bounds__(256) void scan1(
    const int* __restrict__ cnt, int* __restrict__ bsum, int N)
{
    __shared__ int ls[256];
    const int base = blockIdx.x * 1024;
    const int tid = threadIdx.x;
    int s = 0;
#pragma unroll
    for (int i = 0; i < 4; ++i) {
        const int idx = base + tid * 4 + i;
        if (idx < N) s += cnt[idx];
    }
    ls[tid] = s;
    __syncthreads();
    for (int st = 128; st >= 1; st >>= 1) {
        if (tid < st) ls[tid] += ls[tid + st];
        __syncthreads();
    }
    if (tid == 0) bsum[blockIdx.x] = ls[0];
}

__global__ void scan2(int* __restrict__ bsum, int nb)
{
    __shared__ int ls[128];
    const int tid = threadIdx.x;
    const int v = (tid < nb) ? bsum[tid] : 0;
    ls[tid] = v;
    __syncthreads();
    for (int st = 1; st < 128; st <<= 1) {
        const int t = (tid >= st) ? ls[tid - st] : 0;
        __syncthreads();
        ls[tid] += t;
        __syncthreads();
    }
    if (tid < nb) bsum[tid] = ls[tid] - v;  // exclusive
}

__global__ __launch_bounds__(256) void scan3(
    const int* __restrict__ cnt, const int* __restrict__ bsum,
    int* __restrict__ rp, int N)
{
    __shared__ int ls[256];
    const int base = blockIdx.x * 1024;
    const int tid = threadIdx.x;
    int c[4];
    int s = 0;
#pragma unroll
    for (int i = 0; i < 4; ++i) {
        const int idx = base + tid * 4 + i;
        c[i] = (idx < N) ? cnt[idx] : 0;
        s += c[i];
    }
    ls[tid] = s;
    __syncthreads();
    for (int st = 1; st < 256; st <<= 1) {
        const int v = (tid >= st) ? ls[tid - st] : 0;
        __syncthreads();
        ls[tid] += v;
        __syncthreads();
    }
    int excl = ls[tid] - s + bsum[blockIdx.x];
#pragma unroll
    for (int i = 0; i < 4; ++i) {
        const int idx = base + tid * 4 + i;
        if (idx < N) rp[idx] = excl;
        excl += c[i];
    }
}

// counting-sort placement; rp doubles as cursor (after this, rp[n] = end_n)
__global__ __launch_bounds__(256) void reorder(
    const int* __restrict__ src, const int* __restrict__ dst,
    const float* __restrict__ ew, int* __restrict__ rp,
    int2* __restrict__ packed, int E)
{
    const int e = blockIdx.x * 256 + threadIdx.x;
    if (e < E) {
        const int pos = atomicAdd(&rp[dst[e]], 1);
        packed[pos] = make_int2(src[e], __float_as_int(ew[e]));
    }
}

// atomic-free aggregation: one 64-lane wave per node, 2 bf16 cols per lane.
// agg[n,:] = sum_{e: dst==n} w_e * h[src_e,:]    (h bf16, acc fp32)
__global__ __launch_bounds__(256) void aggregate_bf16(
    const int2* __restrict__ packed, const int* __restrict__ rp,
    const unsigned short* __restrict__ h, float* __restrict__ agg, int N)
{
    const int lane = threadIdx.x & 63;
    const int n = (blockIdx.x * 256 + threadIdx.x) >> 6;
    if (n >= N) return;
    const int start = (n == 0) ? 0 : rp[n - 1];
    const int end = rp[n];
    float2 acc = {0.f, 0.f};
    for (int k = start; k < end; ++k) {
        const int2 p = packed[k];
        const float w = __int_as_float(p.y);
        const unsigned v = ((const unsigned*)h)[(size_t)p.x * 64 + lane];
        acc.x = fmaf(w, bf2f((unsigned short)(v & 0xffffu)), acc.x);
        acc.y = fmaf(w, bf2f((unsigned short)(v >> 16)), acc.y);
    }
    ((float2*)agg)[(size_t)n * 64 + lane] = acc;
}

// ---------------- BN / epilogue ----------------

__global__ __launch_bounds__(256) void bn_stats(
    const float* __restrict__ x, float* __restrict__ sum,
    float* __restrict__ sumsq, int N)
{
    __shared__ float4 ls[256], lq[256];
    const int tid = threadIdx.x;
    const int c4 = tid & 31, rr = tid >> 5;
    float4 s = {0, 0, 0, 0}, q = {0, 0, 0, 0};
    for (int row = blockIdx.x * 8 + rr; row < N; row += gridDim.x * 8) {
        const float4 v = ((const float4*)x)[(size_t)row * 32 + c4];
        s.x += v.x; s.y += v.y; s.z += v.z; s.w += v.w;
        q.x += v.x * v.x; q.y += v.y * v.y; q.z += v.z * v.z; q.w += v.w * v.w;
    }
    ls[tid] = s; lq[tid] = q;
    __syncthreads();
    for (int st = 128; st >= 32; st >>= 1) {
        if (tid < st) {
            ls[tid].x += ls[tid + st].x; ls[tid].y += ls[tid + st].y;
            ls[tid].z += ls[tid + st].z; ls[tid].w += ls[tid + st].w;
            lq[tid].x += lq[tid + st].x; lq[tid].y += lq[tid + st].y;
            lq[tid].z += lq[tid + st].z; lq[tid].w += lq[tid + st].w;
        }
        __syncthreads();
    }
    if (tid < 32) {
        const float4 fs = ls[tid], fq = lq[tid];
        atomicAdd(&sum[tid * 4 + 0], fs.x);
        atomicAdd(&sum[tid * 4 + 1], fs.y);
        atomicAdd(&sum[tid * 4 + 2], fs.z);
        atomicAdd(&sum[tid * 4 + 3], fs.w);
        atomicAdd(&sumsq[tid * 4 + 0], fq.x);
        atomicAdd(&sumsq[tid * 4 + 1], fq.y);
        atomicAdd(&sumsq[tid * 4 + 2], fq.z);
        atomicAdd(&sumsq[tid * 4 + 3], fq.w);
    }
}

__global__ void bn_finalize(
    const float* __restrict__ sum, const float* __restrict__ sumsq,
    const float* __restrict__ gamma, const float* __restrict__ beta,
    float* __restrict__ Ax, float* __restrict__ Bx, int N)
{
    const int c = threadIdx.x;  // 128
    const float invN = 1.0f / (float)N;
    const float m = sum[c] * invN;
    const float var = sumsq[c] * invN - m * m;
    const float rs = rsqrtf(var + BN_EPS);
    Ax[c] = gamma[c] * rs;
    Bx[c] = beta[c] - gamma[c] * m * rs;
}

// sout[f] = sum_n cw[n] * relu(A1[f]*x[n,f] + B1[f])
__global__ __launch_bounds__(256) void wcolsum(
    const float* __restrict__ x, const float* __restrict__ cw,
    const float* __restrict__ A1, const float* __restrict__ B1,
    float* __restrict__ sout, int N)
{
    __shared__ float4 ls[256];
    const int tid = threadIdx.x;
    const int c4 = tid & 31, rr = tid >> 5;
    const float4 sa = ((const float4*)A1)[c4];
    const float4 sb = ((const float4*)B1)[c4];
    float4 s = {0, 0, 0, 0};
    for (int row = blockIdx.x * 8 + rr; row < N; row += gridDim.x * 8) {
        float4 v = ((const float4*)x)[(size_t)row * 32 + c4];
        const float c = cw[row];
        v.x = fmaxf(fmaf(sa.x, v.x, sb.x), 0.f);
        v.y = fmaxf(fmaf(sa.y, v.y, sb.y), 0.f);
        v.z = fmaxf(fmaf(sa.z, v.z, sb.z), 0.f);
        v.w = fmaxf(fmaf(sa.w, v.w, sb.w), 0.f);
        s.x = fmaf(c, v.x, s.x); s.y = fmaf(c, v.y, s.y);
        s.z = fmaf(c, v.z, s.z); s.w = fmaf(c, v.w, s.w);
    }
    ls[tid] = s;
    __syncthreads();
    for (int st = 128; st >= 32; st >>= 1) {
        if (tid < st) {
            ls[tid].x += ls[tid + st].x; ls[tid].y += ls[tid + st].y;
            ls[tid].z += ls[tid + st].z; ls[tid].w += ls[tid + st].w;
        }
        __syncthreads();
    }
    if (tid < 32) {
        const float4 fs = ls[tid];
        atomicAdd(&sout[tid * 4 + 0], fs.x);
        atomicAdd(&sout[tid * 4 + 1], fs.y);
        atomicAdd(&sout[tid * 4 + 2], fs.z);
        atomicAdd(&sout[tid * 4 + 3], fs.w);
    }
}

__global__ void final_out(
    const float* __restrict__ s, const float* __restrict__ W2,
    const float* __restrict__ b2, float* __restrict__ out, int N, int Dout)
{
    const int j = threadIdx.x;
    if (j < Dout) {
        float acc = 0.f;
        for (int f = 0; f < 128; ++f) acc = fmaf(s[f], W2[f * Dout + j], acc);
        out[j] = acc + (float)N * b2[j];
    }
}

extern "C" void kernel_launch(void* const* d_in, const int* in_sizes, int n_in,
                              void* d_out, int out_size, void* d_ws, size_t ws_size,
                              hipStream_t stream)
{
    const float* nf  = (const float*)d_in[0];
    const int*   ei  = (const int*)d_in[1];
    const float* ew  = (const float*)d_in[2];
    const float* W0  = (const float*)d_in[3];
    // b0 = d_in[4], b1 = d_in[6]: cancel inside BatchNorm, unused
    const float* W1  = (const float*)d_in[5];
    const float* W2  = (const float*)d_in[7];
    const float* b2  = (const float*)d_in[8];
    const float* g0  = (const float*)d_in[9];
    const float* be0 = (const float*)d_in[10];
    const float* g1  = (const float*)d_in[11];
    const float* be1 = (const float*)d_in[12];

    const int N = in_sizes[0] / 128;
    const int E = in_sizes[2];
    const int* srcI = ei;       // edge_index[0,:]
    const int* dstI = ei + E;   // edge_index[1,:]

    const size_t NB  = (size_t)N * 128 * sizeof(float);          // fp32 feature buf
    const size_t HB  = ((size_t)N * 128 * 2 + 255) & ~(size_t)255; // bf16 h buf
    const size_t NA  = ((size_t)N * sizeof(int) + 255) & ~(size_t)255;
    char* ws = (char*)d_ws;
    size_t off = 0;
    float* cw    = (float*)(ws + off); off += NA;
    int*   cnt   = (int*)  (ws + off); off += NA;
    int*   rp    = (int*)  (ws + off); off += NA;
    int*   bsum  = (int*)  (ws + off); off += 512;
    float* stats = (float*)(ws + off); off += 8192;
    unsigned short* hbuf = (unsigned short*)(ws + off); off += HB;
    float* agg   = (float*)(ws + off); off += NB;
    int2*  packed = (int2*)(ws + off); off += (size_t)E * 8;
    unsigned short* wt0 = (unsigned short*)(ws + off); off += 32768;
    unsigned short* wt1 = (unsigned short*)(ws + off); off += 32768;
    (void)ws_size;  // rounds 1-2 proved ws_size >= 116 MB; this layout needs ~90 MB

    float* sum0 = stats + 0;   float* sq0  = stats + 128;
    float* sum1 = stats + 256; float* sq1  = stats + 384;
    float* A0   = stats + 512; float* B0v  = stats + 640;
    float* A1   = stats + 768; float* B1v  = stats + 896;
    float* svec = stats + 1024;

    const int gemmGrid = (N + 63) / 64;
    const int edgeGrid = (E + 255) / 256;
    const int redGrid  = 1024;
    const int nChunks  = (N + 1023) / 1024;   // 98 <= 128
    const int aggGrid  = (N * 64 + 255) / 256;

    hipMemsetAsync(cw, 0, (size_t)N * sizeof(float), stream);
    hipMemsetAsync(cnt, 0, (size_t)N * sizeof(int), stream);
    hipMemsetAsync(stats, 0, 1280 * sizeof(float), stream);

    // ---- build dst-CSR + weights prep (graph identical both layers) ----
    hist<<<edgeGrid, 256, 0, stream>>>(srcI, dstI, ew, cnt, cw, E);
    scan1<<<nChunks, 256, 0, stream>>>(cnt, bsum, N);
    scan2<<<1, 128, 0, stream>>>(bsum, nChunks);
    scan3<<<nChunks, 256, 0, stream>>>(cnt, bsum, rp, N);
    reorder<<<edgeGrid, 256, 0, stream>>>(srcI, dstI, ew, rp, packed, E);
    wconv<<<64, 256, 0, stream>>>(W0, W1, wt0, wt1);

    // ---- layer 0 ----
    gemm_mfma<false><<<gemmGrid, 256, 0, stream>>>(nf, wt0, hbuf, nullptr, nullptr, N);
    aggregate_bf16<<<aggGrid, 256, 0, stream>>>(packed, rp, hbuf, agg, N);
    bn_stats<<<redGrid, 256, 0, stream>>>(agg, sum0, sq0, N);
    bn_finalize<<<1, 128, 0, stream>>>(sum0, sq0, g0, be0, A0, B0v, N);

    // ---- layer 1 (BN+ReLU of layer 0 fused into GEMM A-staging) ----
    gemm_mfma<true><<<gemmGrid, 256, 0, stream>>>(agg, wt1, hbuf, A0, B0v, N);
    aggregate_bf16<<<aggGrid, 256, 0, stream>>>(packed, rp, hbuf, agg, N);
    bn_stats<<<redGrid, 256, 0, stream>>>(agg, sum1, sq1, N);
    bn_finalize<<<1, 128, 0, stream>>>(sum1, sq1, g1, be1, A1, B1v, N);

    // ---- collapsed layer 2: out = (sum_n cw[n]*x2[n,:]) @ W2 + N*b2 ----
    wcolsum<<<redGrid, 256, 0, stream>>>(agg, cw, A1, B1v, svec, N);
    final_out<<<1, 64, 0, stream>>>(svec, W2, b2, (float*)d_out, N, out_size);
}

// Round 4
// 782.275 us; speedup vs baseline: 7.7851x; 1.3399x over previous
//
#include <hip/hip_runtime.h>

#define BN_EPS 1e-5f

typedef __attribute__((ext_vector_type(8))) short short8;
typedef __attribute__((ext_vector_type(4))) float floatx4;

__device__ __forceinline__ unsigned short f2bf(float f) {
    unsigned u = __float_as_uint(f);
    unsigned r = u + 0x7FFFu + ((u >> 16) & 1u);   // round-to-nearest-even
    return (unsigned short)(r >> 16);
}
__device__ __forceinline__ float blo(unsigned v) { return __uint_as_float(v << 16); }
__device__ __forceinline__ float bhi(unsigned v) { return __uint_as_float(v & 0xffff0000u); }

// ---------------- W pre-transpose: wt[n][k] = bf16(W[k][n]) ----------------
__global__ __launch_bounds__(256) void wconv(
    const float* __restrict__ W0, const float* __restrict__ W1,
    unsigned short* __restrict__ wt0, unsigned short* __restrict__ wt1)
{
    const int idx = blockIdx.x * 256 + threadIdx.x;   // < 16384
    const int n = idx >> 7, k = idx & 127;
    wt0[idx] = f2bf(W0[k * 128 + n]);
    wt1[idx] = f2bf(W1[k * 128 + n]);
}

// ---------------- layer-0 GEMM: C[M x 128] = A_fp32 @ W ----------------
// Wt bf16 [n][k] pre-transposed. Frag layouts m89/m120-verified.
__global__ __launch_bounds__(256) void gemm0(
    const float* __restrict__ A, const unsigned short* __restrict__ Wt,
    unsigned short* __restrict__ C, int M)
{
    __shared__ char lds[53248];
    unsigned short* Al = (unsigned short*)lds;            // [64][136] bf16
    unsigned short* Wl = (unsigned short*)(lds + 17408);  // [128][136] bf16
    float* Cl = (float*)lds;                              // [64][132] f32 (reuse)

    const int tid = threadIdx.x;
    const int r0 = blockIdx.x * 64;

#pragma unroll
    for (int i = 0; i < 16; ++i) {
        const int idx = i * 256 + tid;          // ushort4 units
        const int n = idx >> 5, q = idx & 31;
        const ushort4 v = ((const ushort4*)Wt)[idx];
        *(ushort4*)&Wl[n * 136 + q * 4] = v;
    }
#pragma unroll
    for (int i = 0; i < 8; ++i) {
        const int row = i * 8 + (tid >> 5), q = tid & 31;
        const int gr = r0 + row;
        float4 v = (gr < M) ? ((const float4*)A)[(size_t)gr * 32 + q]
                            : make_float4(0.f, 0.f, 0.f, 0.f);
        ushort4 o;
        o.x = f2bf(v.x); o.y = f2bf(v.y); o.z = f2bf(v.z); o.w = f2bf(v.w);
        *(ushort4*)&Al[row * 136 + q * 4] = o;
    }
    __syncthreads();

    const int wave = tid >> 6, lane = tid & 63;
    const int lrow = lane & 15, quad = lane >> 4;
    const int n0 = wave * 32;

    floatx4 acc[4][2];
#pragma unroll
    for (int mt = 0; mt < 4; ++mt)
#pragma unroll
        for (int t = 0; t < 2; ++t)
#pragma unroll
            for (int j = 0; j < 4; ++j) acc[mt][t][j] = 0.f;

#pragma unroll
    for (int c = 0; c < 4; ++c) {
        const int k0 = c * 32;
        const short8 b0 = *(const short8*)&Wl[(n0 + lrow) * 136 + k0 + quad * 8];
        const short8 b1 = *(const short8*)&Wl[(n0 + 16 + lrow) * 136 + k0 + quad * 8];
#pragma unroll
        for (int mt = 0; mt < 4; ++mt) {
            const short8 a = *(const short8*)&Al[(mt * 16 + lrow) * 136 + k0 + quad * 8];
            acc[mt][0] = __builtin_amdgcn_mfma_f32_16x16x32_bf16(a, b0, acc[mt][0], 0, 0, 0);
            acc[mt][1] = __builtin_amdgcn_mfma_f32_16x16x32_bf16(a, b1, acc[mt][1], 0, 0, 0);
        }
    }
    __syncthreads();

#pragma unroll
    for (int mt = 0; mt < 4; ++mt)
#pragma unroll
        for (int t = 0; t < 2; ++t)
#pragma unroll
            for (int j = 0; j < 4; ++j)
                Cl[(mt * 16 + quad * 4 + j) * 132 + n0 + t * 16 + lrow] = acc[mt][t][j];
    __syncthreads();

#pragma unroll
    for (int i = 0; i < 4; ++i) {
        const int row = i * 16 + (tid >> 4);
        const int c0 = (tid & 15) * 8;
        const int gr = r0 + row;
        if (gr < M) {
            const float4 v0 = *(float4*)&Cl[row * 132 + c0];
            const float4 v1 = *(float4*)&Cl[row * 132 + c0 + 4];
            uint4 o;
            o.x = (unsigned)f2bf(v0.x) | ((unsigned)f2bf(v0.y) << 16);
            o.y = (unsigned)f2bf(v0.z) | ((unsigned)f2bf(v0.w) << 16);
            o.z = (unsigned)f2bf(v1.x) | ((unsigned)f2bf(v1.y) << 16);
            o.w = (unsigned)f2bf(v1.z) | ((unsigned)f2bf(v1.w) << 16);
            ((uint4*)C)[(size_t)gr * 16 + (c0 >> 3)] = o;
        }
    }
}

// ---------------- layer-1 GEMM: C = relu(BN(A_bf16)) @ W ----------------
// BN affine computed in-kernel from raw stats (bn_finalize folded in).
__global__ __launch_bounds__(256) void gemm1(
    const unsigned* __restrict__ Ab,   // bf16 agg, uint = 2 cols
    const unsigned short* __restrict__ Wt,
    unsigned short* __restrict__ C,
    const float* __restrict__ sum, const float* __restrict__ sq,
    const float* __restrict__ g, const float* __restrict__ be,
    int M, int N)
{
    __shared__ char lds[53248];
    unsigned short* Al = (unsigned short*)lds;            // [64][136] bf16
    unsigned short* Wl = (unsigned short*)(lds + 17408);  // [128][136] bf16
    float* AscL = (float*)(lds + 52224);                  // [128]
    float* AshL = AscL + 128;                             // overlaps nothing live
    float* Cl = (float*)lds;                              // reuse after MFMA

    const int tid = threadIdx.x;
    const int r0 = blockIdx.x * 64;

    if (tid < 128) {
        const float invN = 1.0f / (float)N;
        const float m = sum[tid] * invN;
        const float var = sq[tid] * invN - m * m;
        const float rs = rsqrtf(var + BN_EPS);
        AscL[tid] = g[tid] * rs;
        AshL[tid] = be[tid] - g[tid] * m * rs;
    }
    __syncthreads();

#pragma unroll
    for (int i = 0; i < 16; ++i) {
        const int idx = i * 256 + tid;
        const int n = idx >> 5, q = idx & 31;
        const ushort4 v = ((const ushort4*)Wt)[idx];
        *(ushort4*)&Wl[n * 136 + q * 4] = v;
    }
#pragma unroll
    for (int i = 0; i < 4; ++i) {
        const int idx = i * 256 + tid;          // uint4 (8 bf16 cols) units
        const int row = idx >> 4, qc = idx & 15;
        const int gr = r0 + row;
        uint4 v = (gr < M) ? ((const uint4*)Ab)[(size_t)gr * 16 + qc]
                           : make_uint4(0, 0, 0, 0);
        const float4 a0 = *(const float4*)&AscL[qc * 8];
        const float4 a1 = *(const float4*)&AscL[qc * 8 + 4];
        const float4 b0 = *(const float4*)&AshL[qc * 8];
        const float4 b1 = *(const float4*)&AshL[qc * 8 + 4];
        float x0 = fmaxf(fmaf(a0.x, blo(v.x), b0.x), 0.f);
        float x1 = fmaxf(fmaf(a0.y, bhi(v.x), b0.y), 0.f);
        float x2 = fmaxf(fmaf(a0.z, blo(v.y), b0.z), 0.f);
        float x3 = fmaxf(fmaf(a0.w, bhi(v.y), b0.w), 0.f);
        float x4 = fmaxf(fmaf(a1.x, blo(v.z), b1.x), 0.f);
        float x5 = fmaxf(fmaf(a1.y, bhi(v.z), b1.y), 0.f);
        float x6 = fmaxf(fmaf(a1.z, blo(v.w), b1.z), 0.f);
        float x7 = fmaxf(fmaf(a1.w, bhi(v.w), b1.w), 0.f);
        uint4 o;
        o.x = (unsigned)f2bf(x0) | ((unsigned)f2bf(x1) << 16);
        o.y = (unsigned)f2bf(x2) | ((unsigned)f2bf(x3) << 16);
        o.z = (unsigned)f2bf(x4) | ((unsigned)f2bf(x5) << 16);
        o.w = (unsigned)f2bf(x6) | ((unsigned)f2bf(x7) << 16);
        *(uint4*)&Al[row * 136 + qc * 8] = o;
    }
    __syncthreads();

    const int wave = tid >> 6, lane = tid & 63;
    const int lrow = lane & 15, quad = lane >> 4;
    const int n0 = wave * 32;

    floatx4 acc[4][2];
#pragma unroll
    for (int mt = 0; mt < 4; ++mt)
#pragma unroll
        for (int t = 0; t < 2; ++t)
#pragma unroll
            for (int j = 0; j < 4; ++j) acc[mt][t][j] = 0.f;

#pragma unroll
    for (int c = 0; c < 4; ++c) {
        const int k0 = c * 32;
        const short8 b0 = *(const short8*)&Wl[(n0 + lrow) * 136 + k0 + quad * 8];
        const short8 b1 = *(const short8*)&Wl[(n0 + 16 + lrow) * 136 + k0 + quad * 8];
#pragma unroll
        for (int mt = 0; mt < 4; ++mt) {
            const short8 a = *(const short8*)&Al[(mt * 16 + lrow) * 136 + k0 + quad * 8];
            acc[mt][0] = __builtin_amdgcn_mfma_f32_16x16x32_bf16(a, b0, acc[mt][0], 0, 0, 0);
            acc[mt][1] = __builtin_amdgcn_mfma_f32_16x16x32_bf16(a, b1, acc[mt][1], 0, 0, 0);
        }
    }
    __syncthreads();

#pragma unroll
    for (int mt = 0; mt < 4; ++mt)
#pragma unroll
        for (int t = 0; t < 2; ++t)
#pragma unroll
            for (int j = 0; j < 4; ++j)
                Cl[(mt * 16 + quad * 4 + j) * 132 + n0 + t * 16 + lrow] = acc[mt][t][j];
    __syncthreads();

#pragma unroll
    for (int i = 0; i < 4; ++i) {
        const int row = i * 16 + (tid >> 4);
        const int c0 = (tid & 15) * 8;
        const int gr = r0 + row;
        if (gr < M) {
            const float4 v0 = *(float4*)&Cl[row * 132 + c0];
            const float4 v1 = *(float4*)&Cl[row * 132 + c0 + 4];
            uint4 o;
            o.x = (unsigned)f2bf(v0.x) | ((unsigned)f2bf(v0.y) << 16);
            o.y = (unsigned)f2bf(v0.z) | ((unsigned)f2bf(v0.w) << 16);
            o.z = (unsigned)f2bf(v1.x) | ((unsigned)f2bf(v1.y) << 16);
            o.w = (unsigned)f2bf(v1.z) | ((unsigned)f2bf(v1.w) << 16);
            ((uint4*)C)[(size_t)gr * 16 + (c0 >> 3)] = o;
        }
    }
}

// ---------------- CSR build (counting sort by dst) ----------------

__global__ __launch_bounds__(256) void hist(
    const int* __restrict__ src, const int* __restrict__ dst,
    const float* __restrict__ ew, int* __restrict__ cnt,
    float* __restrict__ cw, int E)
{
    const int e = blockIdx.x * 256 + threadIdx.x;
    if (e < E) {
        atomicAdd(&cnt[dst[e]], 1);
        atomicAdd(&cw[src[e]], ew[e]);
    }
}

__global__ __launch_bounds__(256) void scan1(
    const int* __restrict__ cnt, int* __restrict__ bsum, int N)
{
    __shared__ int ls[256];
    const int base = blockIdx.x * 1024;
    const int tid = threadIdx.x;
    int s = 0;
#pragma unroll
    for (int i = 0; i < 4; ++i) {
        const int idx = base + tid * 4 + i;
        if (idx < N) s += cnt[idx];
    }
    ls[tid] = s;
    __syncthreads();
    for (int st = 128; st >= 1; st >>= 1) {
        if (tid < st) ls[tid] += ls[tid + st];
        __syncthreads();
    }
    if (tid == 0) bsum[blockIdx.x] = ls[0];
}

__global__ void scan2(int* __restrict__ bsum, int nb)
{
    __shared__ int ls[128];
    const int tid = threadIdx.x;
    const int v = (tid < nb) ? bsum[tid] : 0;
    ls[tid] = v;
    __syncthreads();
    for (int st = 1; st < 128; st <<= 1) {
        const int t = (tid >= st) ? ls[tid - st] : 0;
        __syncthreads();
        ls[tid] += t;
        __syncthreads();
    }
    if (tid < nb) bsum[tid] = ls[tid] - v;  // exclusive
}

__global__ __launch_bounds__(256) void scan3(
    const int* __restrict__ cnt, const int* __restrict__ bsum,
    int* __restrict__ rp, int N)
{
    __shared__ int ls[256];
    const int base = blockIdx.x * 1024;
    const int tid = threadIdx.x;
    int c[4];
    int s = 0;
#pragma unroll
    for (int i = 0; i < 4; ++i) {
        const int idx = base + tid * 4 + i;
        c[i] = (idx < N) ? cnt[idx] : 0;
        s += c[i];
    }
    ls[tid] = s;
    __syncthreads();
    for (int st = 1; st < 256; st <<= 1) {
        const int v = (tid >= st) ? ls[tid - st] : 0;
        __syncthreads();
        ls[tid] += v;
        __syncthreads();
    }
    int excl = ls[tid] - s + bsum[blockIdx.x];
#pragma unroll
    for (int i = 0; i < 4; ++i) {
        const int idx = base + tid * 4 + i;
        if (idx < N) rp[idx] = excl;
        excl += c[i];
    }
}

__global__ __launch_bounds__(256) void reorder(
    const int* __restrict__ src, const int* __restrict__ dst,
    const float* __restrict__ ew, int* __restrict__ rp,
    int2* __restrict__ packed, int E)
{
    const int e = blockIdx.x * 256 + threadIdx.x;
    if (e < E) {
        const int pos = atomicAdd(&rp[dst[e]], 1);
        packed[pos] = make_int2(src[e], __float_as_int(ew[e]));
    }
}

// ---------------- fused aggregate + BN stats ----------------
// One wave per AGG_R consecutive nodes; lane l holds cols {2l, 2l+1}.
// Edges prefetched 64-wide (coalesced), broadcast via v_readlane; gathers
// unrolled 4x for MLP. Writes agg bf16; accumulates column sum/sumsq and
// reduces per-block -> 128 atomics each.
#define AGG_R 16
__global__ __launch_bounds__(256) void aggregate_fused(
    const int2* __restrict__ packed, const int* __restrict__ rp,
    const unsigned* __restrict__ h, unsigned* __restrict__ aggb,
    float* __restrict__ sum, float* __restrict__ sq, int N)
{
    const int tid = threadIdx.x;
    const int lane = tid & 63, wave = tid >> 6;
    const int n0 = (blockIdx.x * 4 + wave) * AGG_R;
    float2 csum = {0.f, 0.f}, csq = {0.f, 0.f};

    for (int r = 0; r < AGG_R; ++r) {
        const int n = n0 + r;
        if (n >= N) break;
        int start = (n == 0) ? 0 : rp[n - 1];
        int end = rp[n];
        start = __builtin_amdgcn_readfirstlane(start);
        end = __builtin_amdgcn_readfirstlane(end);
        float2 acc = {0.f, 0.f};
        for (int base = start; base < end; base += 64) {
            const int rem = end - base;
            const int cnt = rem < 64 ? rem : 64;
            int2 myE = make_int2(0, 0);
            if (lane < cnt) myE = packed[base + lane];
            int j = 0;
            for (; j + 4 <= cnt; j += 4) {
                const int s0 = __builtin_amdgcn_readlane(myE.x, j + 0);
                const int s1 = __builtin_amdgcn_readlane(myE.x, j + 1);
                const int s2 = __builtin_amdgcn_readlane(myE.x, j + 2);
                const int s3 = __builtin_amdgcn_readlane(myE.x, j + 3);
                const float w0 = __uint_as_float(__builtin_amdgcn_readlane(myE.y, j + 0));
                const float w1 = __uint_as_float(__builtin_amdgcn_readlane(myE.y, j + 1));
                const float w2 = __uint_as_float(__builtin_amdgcn_readlane(myE.y, j + 2));
                const float w3 = __uint_as_float(__builtin_amdgcn_readlane(myE.y, j + 3));
                const unsigned v0 = h[(size_t)s0 * 64 + lane];
                const unsigned v1 = h[(size_t)s1 * 64 + lane];
                const unsigned v2 = h[(size_t)s2 * 64 + lane];
                const unsigned v3 = h[(size_t)s3 * 64 + lane];
                acc.x = fmaf(w0, blo(v0), acc.x); acc.y = fmaf(w0, bhi(v0), acc.y);
                acc.x = fmaf(w1, blo(v1), acc.x); acc.y = fmaf(w1, bhi(v1), acc.y);
                acc.x = fmaf(w2, blo(v2), acc.x); acc.y = fmaf(w2, bhi(v2), acc.y);
                acc.x = fmaf(w3, blo(v3), acc.x); acc.y = fmaf(w3, bhi(v3), acc.y);
            }
            for (; j < cnt; ++j) {
                const int s0 = __builtin_amdgcn_readlane(myE.x, j);
                const float w0 = __uint_as_float(__builtin_amdgcn_readlane(myE.y, j));
                const unsigned v0 = h[(size_t)s0 * 64 + lane];
                acc.x = fmaf(w0, blo(v0), acc.x); acc.y = fmaf(w0, bhi(v0), acc.y);
            }
        }
        aggb[(size_t)n * 64 + lane] =
            (unsigned)f2bf(acc.x) | ((unsigned)f2bf(acc.y) << 16);
        csum.x += acc.x; csum.y += acc.y;
        csq.x = fmaf(acc.x, acc.x, csq.x);
        csq.y = fmaf(acc.y, acc.y, csq.y);
    }

    __shared__ float2 lsum[256], lsq[256];
    lsum[tid] = csum; lsq[tid] = csq;
    __syncthreads();
    if (tid < 64) {
        float sx = lsum[tid].x + lsum[64 + tid].x + lsum[128 + tid].x + lsum[192 + tid].x;
        float sy = lsum[tid].y + lsum[64 + tid].y + lsum[128 + tid].y + lsum[192 + tid].y;
        float qx = lsq[tid].x + lsq[64 + tid].x + lsq[128 + tid].x + lsq[192 + tid].x;
        float qy = lsq[tid].y + lsq[64 + tid].y + lsq[128 + tid].y + lsq[192 + tid].y;
        atomicAdd(&sum[2 * tid + 0], sx);
        atomicAdd(&sum[2 * tid + 1], sy);
        atomicAdd(&sq[2 * tid + 0], qx);
        atomicAdd(&sq[2 * tid + 1], qy);
    }
}

// ---------------- collapsed layer 2 ----------------
// sout[f] = sum_n cw[n] * relu(A1[f]*x[n,f] + B1[f]);  affine from raw stats.
__global__ __launch_bounds__(256) void wcolsum_bf16(
    const unsigned* __restrict__ xb, const float* __restrict__ cw,
    const float* __restrict__ sum1, const float* __restrict__ sq1,
    const float* __restrict__ g, const float* __restrict__ be,
    float* __restrict__ sout, int N)
{
    __shared__ float Aaf[128], Baf[128];
    __shared__ float2 ls[256];
    const int tid = threadIdx.x;
    if (tid < 128) {
        const float invN = 1.0f / (float)N;
        const float m = sum1[tid] * invN;
        const float var = sq1[tid] * invN - m * m;
        const float rs = rsqrtf(var + BN_EPS);
        Aaf[tid] = g[tid] * rs;
        Baf[tid] = be[tid] - g[tid] * m * rs;
    }
    __syncthreads();
    const int u = tid & 63, rr = tid >> 6;
    const float ax = Aaf[2 * u], ay = Aaf[2 * u + 1];
    const float bx = Baf[2 * u], by = Baf[2 * u + 1];
    float2 s = {0.f, 0.f};
    for (int row = blockIdx.x * 4 + rr; row < N; row += gridDim.x * 4) {
        const unsigned v = xb[(size_t)row * 64 + u];
        const float c = cw[row];
        const float x = fmaxf(fmaf(ax, blo(v), bx), 0.f);
        const float y = fmaxf(fmaf(ay, bhi(v), by), 0.f);
        s.x = fmaf(c, x, s.x);
        s.y = fmaf(c, y, s.y);
    }
    ls[tid] = s;
    __syncthreads();
    if (tid < 64) {
        float sx = ls[tid].x + ls[64 + tid].x + ls[128 + tid].x + ls[192 + tid].x;
        float sy = ls[tid].y + ls[64 + tid].y + ls[128 + tid].y + ls[192 + tid].y;
        atomicAdd(&sout[2 * tid + 0], sx);
        atomicAdd(&sout[2 * tid + 1], sy);
    }
}

__global__ void final_out(
    const float* __restrict__ s, const float* __restrict__ W2,
    const float* __restrict__ b2, float* __restrict__ out, int N, int Dout)
{
    const int j = threadIdx.x;
    if (j < Dout) {
        float acc = 0.f;
        for (int f = 0; f < 128; ++f) acc = fmaf(s[f], W2[f * Dout + j], acc);
        out[j] = acc + (float)N * b2[j];
    }
}

extern "C" void kernel_launch(void* const* d_in, const int* in_sizes, int n_in,
                              void* d_out, int out_size, void* d_ws, size_t ws_size,
                              hipStream_t stream)
{
    const float* nf  = (const float*)d_in[0];
    const int*   ei  = (const int*)d_in[1];
    const float* ew  = (const float*)d_in[2];
    const float* W0  = (const float*)d_in[3];
    // b0 = d_in[4], b1 = d_in[6]: cancel inside BatchNorm, unused
    const float* W1  = (const float*)d_in[5];
    const float* W2  = (const float*)d_in[7];
    const float* b2  = (const float*)d_in[8];
    const float* g0  = (const float*)d_in[9];
    const float* be0 = (const float*)d_in[10];
    const float* g1  = (const float*)d_in[11];
    const float* be1 = (const float*)d_in[12];

    const int N = in_sizes[0] / 128;
    const int E = in_sizes[2];
    const int* srcI = ei;       // edge_index[0,:]
    const int* dstI = ei + E;   // edge_index[1,:]

    const size_t HB = ((size_t)N * 128 * 2 + 255) & ~(size_t)255;  // bf16 buf
    const size_t NA = ((size_t)N * sizeof(int) + 255) & ~(size_t)255;
    char* ws = (char*)d_ws;
    size_t off = 0;
    float* cw    = (float*)(ws + off); off += NA;
    int*   cnt   = (int*)  (ws + off); off += NA;
    int*   rp    = (int*)  (ws + off); off += NA;
    int*   bsum  = (int*)  (ws + off); off += 512;
    float* stats = (float*)(ws + off); off += 4096;
    unsigned short* hbuf = (unsigned short*)(ws + off); off += HB;  // h (bf16)
    unsigned* aggb = (unsigned*)(ws + off); off += HB;              // agg (bf16)
    int2*  packed = (int2*)(ws + off); off += (size_t)E * 8;
    unsigned short* wt0 = (unsigned short*)(ws + off); off += 32768;
    unsigned short* wt1 = (unsigned short*)(ws + off); off += 32768;
    (void)ws_size;  // rounds 1-3 proved ws_size >= 116 MB; this needs ~66 MB

    float* sum0 = stats + 0;   float* sq0 = stats + 128;
    float* sum1 = stats + 256; float* sq1 = stats + 384;
    float* svec = stats + 512;

    const int gemmGrid = (N + 63) / 64;
    const int edgeGrid = (E + 255) / 256;
    const int nChunks  = (N + 1023) / 1024;          // 98 <= 128
    const int aggGrid  = (N + 4 * AGG_R - 1) / (4 * AGG_R);

    hipMemsetAsync(cw, 0, (size_t)N * sizeof(float), stream);
    hipMemsetAsync(cnt, 0, (size_t)N * sizeof(int), stream);
    hipMemsetAsync(stats, 0, 640 * sizeof(float), stream);

    // ---- CSR build + weight prep (graph identical both layers) ----
    hist<<<edgeGrid, 256, 0, stream>>>(srcI, dstI, ew, cnt, cw, E);
    scan1<<<nChunks, 256, 0, stream>>>(cnt, bsum, N);
    scan2<<<1, 128, 0, stream>>>(bsum, nChunks);
    scan3<<<nChunks, 256, 0, stream>>>(cnt, bsum, rp, N);
    reorder<<<edgeGrid, 256, 0, stream>>>(srcI, dstI, ew, rp, packed, E);
    wconv<<<64, 256, 0, stream>>>(W0, W1, wt0, wt1);

    // ---- layer 0 ----
    gemm0<<<gemmGrid, 256, 0, stream>>>(nf, wt0, hbuf, N);
    aggregate_fused<<<aggGrid, 256, 0, stream>>>(
        packed, rp, (const unsigned*)hbuf, aggb, sum0, sq0, N);

    // ---- layer 1 (BN0+ReLU folded into GEMM staging) ----
    gemm1<<<gemmGrid, 256, 0, stream>>>(aggb, wt1, hbuf, sum0, sq0, g0, be0, N, N);
    aggregate_fused<<<aggGrid, 256, 0, stream>>>(
        packed, rp, (const unsigned*)hbuf, aggb, sum1, sq1, N);

    // ---- collapsed layer 2: out = (sum_n cw[n]*relu(BN1(x2))[n,:]) @ W2 + N*b2 ----
    wcolsum_bf16<<<2048, 256, 0, stream>>>(aggb, cw, sum1, sq1, g1, be1, svec, N);
    final_out<<<1, 64, 0, stream>>>(svec, W2, b2, (float*)d_out, N, out_size);
}

// Round 5
// 634.130 us; speedup vs baseline: 9.6038x; 1.2336x over previous
//
#include <hip/hip_runtime.h>

#define BN_EPS 1e-5f

// Bucket-sort parameters: NPB nodes per bucket (pow2), PB placement blocks.
// B = ceil(N/NPB) must be <= MAXB (N=100000 -> B=196).
#define NPB 512
#define NPB_SHIFT 9
#define PB 512
#define MAXB 256

typedef __attribute__((ext_vector_type(8))) short short8;
typedef __attribute__((ext_vector_type(4))) float floatx4;

__device__ __forceinline__ unsigned short f2bf(float f) {
    unsigned u = __float_as_uint(f);
    unsigned r = u + 0x7FFFu + ((u >> 16) & 1u);   // round-to-nearest-even
    return (unsigned short)(r >> 16);
}
__device__ __forceinline__ float blo(unsigned v) { return __uint_as_float(v << 16); }
__device__ __forceinline__ float bhi(unsigned v) { return __uint_as_float(v & 0xffff0000u); }

// ---------------- W pre-transpose: wt[n][k] = bf16(W[k][n]) ----------------
__global__ __launch_bounds__(256) void wconv(
    const float* __restrict__ W0, const float* __restrict__ W1,
    unsigned short* __restrict__ wt0, unsigned short* __restrict__ wt1)
{
    const int idx = blockIdx.x * 256 + threadIdx.x;   // < 16384
    const int n = idx >> 7, k = idx & 127;
    wt0[idx] = f2bf(W0[k * 128 + n]);
    wt1[idx] = f2bf(W1[k * 128 + n]);
}

// ---------------- layer-0 GEMM: C[M x 128] = A_fp32 @ W ----------------
__global__ __launch_bounds__(256) void gemm0(
    const float* __restrict__ A, const unsigned short* __restrict__ Wt,
    unsigned short* __restrict__ C, int M)
{
    __shared__ char lds[53248];
    unsigned short* Al = (unsigned short*)lds;            // [64][136] bf16
    unsigned short* Wl = (unsigned short*)(lds + 17408);  // [128][136] bf16
    float* Cl = (float*)lds;                              // [64][132] f32 (reuse)

    const int tid = threadIdx.x;
    const int r0 = blockIdx.x * 64;

#pragma unroll
    for (int i = 0; i < 16; ++i) {
        const int idx = i * 256 + tid;          // ushort4 units
        const int n = idx >> 5, q = idx & 31;
        const ushort4 v = ((const ushort4*)Wt)[idx];
        *(ushort4*)&Wl[n * 136 + q * 4] = v;
    }
#pragma unroll
    for (int i = 0; i < 8; ++i) {
        const int row = i * 8 + (tid >> 5), q = tid & 31;
        const int gr = r0 + row;
        float4 v = (gr < M) ? ((const float4*)A)[(size_t)gr * 32 + q]
                            : make_float4(0.f, 0.f, 0.f, 0.f);
        ushort4 o;
        o.x = f2bf(v.x); o.y = f2bf(v.y); o.z = f2bf(v.z); o.w = f2bf(v.w);
        *(ushort4*)&Al[row * 136 + q * 4] = o;
    }
    __syncthreads();

    const int wave = tid >> 6, lane = tid & 63;
    const int lrow = lane & 15, quad = lane >> 4;
    const int n0 = wave * 32;

    floatx4 acc[4][2];
#pragma unroll
    for (int mt = 0; mt < 4; ++mt)
#pragma unroll
        for (int t = 0; t < 2; ++t)
#pragma unroll
            for (int j = 0; j < 4; ++j) acc[mt][t][j] = 0.f;

#pragma unroll
    for (int c = 0; c < 4; ++c) {
        const int k0 = c * 32;
        const short8 b0 = *(const short8*)&Wl[(n0 + lrow) * 136 + k0 + quad * 8];
        const short8 b1 = *(const short8*)&Wl[(n0 + 16 + lrow) * 136 + k0 + quad * 8];
#pragma unroll
        for (int mt = 0; mt < 4; ++mt) {
            const short8 a = *(const short8*)&Al[(mt * 16 + lrow) * 136 + k0 + quad * 8];
            acc[mt][0] = __builtin_amdgcn_mfma_f32_16x16x32_bf16(a, b0, acc[mt][0], 0, 0, 0);
            acc[mt][1] = __builtin_amdgcn_mfma_f32_16x16x32_bf16(a, b1, acc[mt][1], 0, 0, 0);
        }
    }
    __syncthreads();

#pragma unroll
    for (int mt = 0; mt < 4; ++mt)
#pragma unroll
        for (int t = 0; t < 2; ++t)
#pragma unroll
            for (int j = 0; j < 4; ++j)
                Cl[(mt * 16 + quad * 4 + j) * 132 + n0 + t * 16 + lrow] = acc[mt][t][j];
    __syncthreads();

#pragma unroll
    for (int i = 0; i < 4; ++i) {
        const int row = i * 16 + (tid >> 4);
        const int c0 = (tid & 15) * 8;
        const int gr = r0 + row;
        if (gr < M) {
            const float4 v0 = *(float4*)&Cl[row * 132 + c0];
            const float4 v1 = *(float4*)&Cl[row * 132 + c0 + 4];
            uint4 o;
            o.x = (unsigned)f2bf(v0.x) | ((unsigned)f2bf(v0.y) << 16);
            o.y = (unsigned)f2bf(v0.z) | ((unsigned)f2bf(v0.w) << 16);
            o.z = (unsigned)f2bf(v1.x) | ((unsigned)f2bf(v1.y) << 16);
            o.w = (unsigned)f2bf(v1.z) | ((unsigned)f2bf(v1.w) << 16);
            ((uint4*)C)[(size_t)gr * 16 + (c0 >> 3)] = o;
        }
    }
}

// ---------------- layer-1 GEMM: C = relu(BN(A_bf16)) @ W ----------------
__global__ __launch_bounds__(256) void gemm1(
    const unsigned* __restrict__ Ab, const unsigned short* __restrict__ Wt,
    unsigned short* __restrict__ C,
    const float* __restrict__ sum, const float* __restrict__ sq,
    const float* __restrict__ g, const float* __restrict__ be,
    int M, int N)
{
    __shared__ char lds[53248];
    unsigned short* Al = (unsigned short*)lds;            // [64][136]
    unsigned short* Wl = (unsigned short*)(lds + 17408);  // [128][136]
    float* AscL = (float*)(lds + 52224);                  // [128]
    float* AshL = AscL + 128;
    float* Cl = (float*)lds;

    const int tid = threadIdx.x;
    const int r0 = blockIdx.x * 64;

    if (tid < 128) {
        const float invN = 1.0f / (float)N;
        const float m = sum[tid] * invN;
        const float var = sq[tid] * invN - m * m;
        const float rs = rsqrtf(var + BN_EPS);
        AscL[tid] = g[tid] * rs;
        AshL[tid] = be[tid] - g[tid] * m * rs;
    }
    __syncthreads();

#pragma unroll
    for (int i = 0; i < 16; ++i) {
        const int idx = i * 256 + tid;
        const int n = idx >> 5, q = idx & 31;
        const ushort4 v = ((const ushort4*)Wt)[idx];
        *(ushort4*)&Wl[n * 136 + q * 4] = v;
    }
#pragma unroll
    for (int i = 0; i < 4; ++i) {
        const int idx = i * 256 + tid;
        const int row = idx >> 4, qc = idx & 15;
        const int gr = r0 + row;
        uint4 v = (gr < M) ? ((const uint4*)Ab)[(size_t)gr * 16 + qc]
                           : make_uint4(0, 0, 0, 0);
        const float4 a0 = *(const float4*)&AscL[qc * 8];
        const float4 a1 = *(const float4*)&AscL[qc * 8 + 4];
        const float4 b0 = *(const float4*)&AshL[qc * 8];
        const float4 b1 = *(const float4*)&AshL[qc * 8 + 4];
        float x0 = fmaxf(fmaf(a0.x, blo(v.x), b0.x), 0.f);
        float x1 = fmaxf(fmaf(a0.y, bhi(v.x), b0.y), 0.f);
        float x2 = fmaxf(fmaf(a0.z, blo(v.y), b0.z), 0.f);
        float x3 = fmaxf(fmaf(a0.w, bhi(v.y), b0.w), 0.f);
        float x4 = fmaxf(fmaf(a1.x, blo(v.z), b1.x), 0.f);
        float x5 = fmaxf(fmaf(a1.y, bhi(v.z), b1.y), 0.f);
        float x6 = fmaxf(fmaf(a1.z, blo(v.w), b1.z), 0.f);
        float x7 = fmaxf(fmaf(a1.w, bhi(v.w), b1.w), 0.f);
        uint4 o;
        o.x = (unsigned)f2bf(x0) | ((unsigned)f2bf(x1) << 16);
        o.y = (unsigned)f2bf(x2) | ((unsigned)f2bf(x3) << 16);
        o.z = (unsigned)f2bf(x4) | ((unsigned)f2bf(x5) << 16);
        o.w = (unsigned)f2bf(x6) | ((unsigned)f2bf(x7) << 16);
        *(uint4*)&Al[row * 136 + qc * 8] = o;
    }
    __syncthreads();

    const int wave = tid >> 6, lane = tid & 63;
    const int lrow = lane & 15, quad = lane >> 4;
    const int n0 = wave * 32;

    floatx4 acc[4][2];
#pragma unroll
    for (int mt = 0; mt < 4; ++mt)
#pragma unroll
        for (int t = 0; t < 2; ++t)
#pragma unroll
            for (int j = 0; j < 4; ++j) acc[mt][t][j] = 0.f;

#pragma unroll
    for (int c = 0; c < 4; ++c) {
        const int k0 = c * 32;
        const short8 b0 = *(const short8*)&Wl[(n0 + lrow) * 136 + k0 + quad * 8];
        const short8 b1 = *(const short8*)&Wl[(n0 + 16 + lrow) * 136 + k0 + quad * 8];
#pragma unroll
        for (int mt = 0; mt < 4; ++mt) {
            const short8 a = *(const short8*)&Al[(mt * 16 + lrow) * 136 + k0 + quad * 8];
            acc[mt][0] = __builtin_amdgcn_mfma_f32_16x16x32_bf16(a, b0, acc[mt][0], 0, 0, 0);
            acc[mt][1] = __builtin_amdgcn_mfma_f32_16x16x32_bf16(a, b1, acc[mt][1], 0, 0, 0);
        }
    }
    __syncthreads();

#pragma unroll
    for (int mt = 0; mt < 4; ++mt)
#pragma unroll
        for (int t = 0; t < 2; ++t)
#pragma unroll
            for (int j = 0; j < 4; ++j)
                Cl[(mt * 16 + quad * 4 + j) * 132 + n0 + t * 16 + lrow] = acc[mt][t][j];
    __syncthreads();

#pragma unroll
    for (int i = 0; i < 4; ++i) {
        const int row = i * 16 + (tid >> 4);
        const int c0 = (tid & 15) * 8;
        const int gr = r0 + row;
        if (gr < M) {
            const float4 v0 = *(float4*)&Cl[row * 132 + c0];
            const float4 v1 = *(float4*)&Cl[row * 132 + c0 + 4];
            uint4 o;
            o.x = (unsigned)f2bf(v0.x) | ((unsigned)f2bf(v0.y) << 16);
            o.y = (unsigned)f2bf(v0.z) | ((unsigned)f2bf(v0.w) << 16);
            o.z = (unsigned)f2bf(v1.x) | ((unsigned)f2bf(v1.y) << 16);
            o.w = (unsigned)f2bf(v1.z) | ((unsigned)f2bf(v1.w) << 16);
            ((uint4*)C)[(size_t)gr * 16 + (c0 >> 3)] = o;
        }
    }
}

// ============ atomic-free CSR build: two-level bucket counting sort ============
// Level 1: bucket edges by dst>>9 (and by src>>9 for cw) with exact
// per-(bucket,block) cursors -> zero global atomics, stable placement.
// Level 2: per-bucket LDS counting sort -> rp[] + packed[]; per-bucket LDS
// float sums -> cw[].

// K1: per-block LDS histograms over buckets; cnt layout [B][PB]
__global__ __launch_bounds__(256) void bucket_hist(
    const int* __restrict__ src, const int* __restrict__ dst,
    int* __restrict__ cntD, int* __restrict__ cntS, int E, int B, int chunk)
{
    __shared__ int hD[MAXB], hS[MAXB];
    const int tid = threadIdx.x;
    for (int i = tid; i < B; i += 256) { hD[i] = 0; hS[i] = 0; }
    __syncthreads();
    const int lo = blockIdx.x * chunk;
    const int hi = min(E, lo + chunk);
    for (int e = lo + tid; e < hi; e += 256) {
        atomicAdd(&hD[dst[e] >> NPB_SHIFT], 1);
        atomicAdd(&hS[src[e] >> NPB_SHIFT], 1);
    }
    __syncthreads();
    for (int i = tid; i < B; i += 256) {
        cntD[i * PB + blockIdx.x] = hD[i];
        cntS[i * PB + blockIdx.x] = hS[i];
    }
}

// K2a: bucket totals + exclusive scan -> baseD/baseS (with sentinel [B]=E)
__global__ __launch_bounds__(256) void bucket_base(
    const int* __restrict__ cntD, const int* __restrict__ cntS,
    int* __restrict__ baseD, int* __restrict__ baseS, int B, int E)
{
    __shared__ int lD[256], lS[256];
    const int tid = threadIdx.x;
    int sD = 0, sS = 0;
    if (tid < B) {
        const int4* pD = (const int4*)(cntD + tid * PB);
        const int4* pS = (const int4*)(cntS + tid * PB);
        for (int j = 0; j < PB / 4; ++j) {
            const int4 a = pD[j], b = pS[j];
            sD += a.x + a.y + a.z + a.w;
            sS += b.x + b.y + b.z + b.w;
        }
    }
    lD[tid] = sD; lS[tid] = sS;
    __syncthreads();
    for (int st = 1; st < 256; st <<= 1) {
        const int vD = (tid >= st) ? lD[tid - st] : 0;
        const int vS = (tid >= st) ? lS[tid - st] : 0;
        __syncthreads();
        lD[tid] += vD; lS[tid] += vS;
        __syncthreads();
    }
    if (tid < B) { baseD[tid] = lD[tid] - sD; baseS[tid] = lS[tid] - sS; }
    if (tid == 0) { baseD[B] = E; baseS[B] = E; }
}

// K2b: convert each bucket row of counts into absolute per-block cursors
__global__ __launch_bounds__(256) void bucket_cursor(
    int* __restrict__ cntD, int* __restrict__ cntS,
    const int* __restrict__ baseD, const int* __restrict__ baseS, int B)
{
    int b = blockIdx.x;
    int* cnt; const int* base;
    if (b < B) { cnt = cntD; base = baseD; }
    else       { cnt = cntS; base = baseS; b -= B; }
    __shared__ int ls[256];
    const int tid = threadIdx.x;
    const int c0 = cnt[b * PB + 2 * tid];
    const int c1 = cnt[b * PB + 2 * tid + 1];
    const int s = c0 + c1;
    ls[tid] = s;
    __syncthreads();
    for (int st = 1; st < 256; st <<= 1) {
        const int v = (tid >= st) ? ls[tid - st] : 0;
        __syncthreads();
        ls[tid] += v;
        __syncthreads();
    }
    const int excl = ls[tid] - s + base[b];
    cnt[b * PB + 2 * tid] = excl;
    cnt[b * PB + 2 * tid + 1] = excl + c0;
}

// K3: place edges into dst-bucketed and src-bucketed record arrays.
// bktD record: { (src<<9)|dstLow , w_bits } ; bktS record: { srcLow, w_bits }
__global__ __launch_bounds__(256) void bucket_place(
    const int* __restrict__ src, const int* __restrict__ dst,
    const float* __restrict__ ew,
    const int* __restrict__ curD, const int* __restrict__ curS,
    uint2* __restrict__ bktD, uint2* __restrict__ bktS, int E, int B, int chunk)
{
    __shared__ int cD[MAXB], cS[MAXB];
    const int tid = threadIdx.x;
    for (int i = tid; i < B; i += 256) {
        cD[i] = curD[i * PB + blockIdx.x];
        cS[i] = curS[i * PB + blockIdx.x];
    }
    __syncthreads();
    const int lo = blockIdx.x * chunk;
    const int hi = min(E, lo + chunk);
    for (int e = lo + tid; e < hi; e += 256) {
        const int s = src[e], d = dst[e];
        const unsigned wb = __float_as_uint(ew[e]);
        const int pd = atomicAdd(&cD[d >> NPB_SHIFT], 1);
        bktD[pd] = make_uint2(((unsigned)s << NPB_SHIFT) | (unsigned)(d & (NPB - 1)), wb);
        const int ps = atomicAdd(&cS[s >> NPB_SHIFT], 1);
        bktS[ps] = make_uint2((unsigned)(s & (NPB - 1)), wb);
    }
}

// K4: per-bucket counting sort by dstLow -> rp[] (end ptrs) + packed[]
__global__ __launch_bounds__(256) void bucket_sort(
    const uint2* __restrict__ bktD, const int* __restrict__ baseD,
    int* __restrict__ rp, int2* __restrict__ packed, int N)
{
    const int b = blockIdx.x;
    const int lo = baseD[b], hi = baseD[b + 1];
    __shared__ int cnt[NPB], cur[NPB];
    __shared__ int ls[256];
    const int tid = threadIdx.x;
    cnt[2 * tid] = 0; cnt[2 * tid + 1] = 0;
    __syncthreads();
    for (int i = lo + tid; i < hi; i += 256)
        atomicAdd(&cnt[bktD[i].x & (NPB - 1)], 1);
    __syncthreads();
    const int c0 = cnt[2 * tid], c1 = cnt[2 * tid + 1];
    const int s = c0 + c1;
    ls[tid] = s;
    __syncthreads();
    for (int st = 1; st < 256; st <<= 1) {
        const int v = (tid >= st) ? ls[tid - st] : 0;
        __syncthreads();
        ls[tid] += v;
        __syncthreads();
    }
    const int excl = ls[tid] - s;
    const int n0 = b * NPB + 2 * tid;
    if (n0 < N)     rp[n0]     = lo + excl + c0;
    if (n0 + 1 < N) rp[n0 + 1] = lo + excl + c0 + c1;
    cur[2 * tid]     = lo + excl;
    cur[2 * tid + 1] = lo + excl + c0;
    __syncthreads();
    for (int i = lo + tid; i < hi; i += 256) {
        const uint2 r = bktD[i];
        const int pos = atomicAdd(&cur[r.x & (NPB - 1)], 1);
        packed[pos] = make_int2((int)(r.x >> NPB_SHIFT), (int)r.y);
    }
}

// K5: per-bucket src-weight sums -> cw[] (coalesced write, no global atomics)
__global__ __launch_bounds__(256) void bucket_cw(
    const uint2* __restrict__ bktS, const int* __restrict__ baseS,
    float* __restrict__ cw, int N)
{
    const int b = blockIdx.x;
    const int lo = baseS[b], hi = baseS[b + 1];
    __shared__ float sm[NPB];
    const int tid = threadIdx.x;
    sm[2 * tid] = 0.f; sm[2 * tid + 1] = 0.f;
    __syncthreads();
    for (int i = lo + tid; i < hi; i += 256) {
        const uint2 r = bktS[i];
        atomicAdd(&sm[r.x], __uint_as_float(r.y));
    }
    __syncthreads();
    const int n0 = b * NPB + 2 * tid;
    if (n0 < N)     cw[n0]     = sm[2 * tid];
    if (n0 + 1 < N) cw[n0 + 1] = sm[2 * tid + 1];
}

// ---------------- fused aggregate + BN stats ----------------
#define AGG_R 16
__global__ __launch_bounds__(256) void aggregate_fused(
    const int2* __restrict__ packed, const int* __restrict__ rp,
    const unsigned* __restrict__ h, unsigned* __restrict__ aggb,
    float* __restrict__ sum, float* __restrict__ sq, int N)
{
    const int tid = threadIdx.x;
    const int lane = tid & 63, wave = tid >> 6;
    const int n0 = (blockIdx.x * 4 + wave) * AGG_R;
    float2 csum = {0.f, 0.f}, csq = {0.f, 0.f};

    for (int r = 0; r < AGG_R; ++r) {
        const int n = n0 + r;
        if (n >= N) break;
        int start = (n == 0) ? 0 : rp[n - 1];
        int end = rp[n];
        start = __builtin_amdgcn_readfirstlane(start);
        end = __builtin_amdgcn_readfirstlane(end);
        float2 acc = {0.f, 0.f};
        for (int base = start; base < end; base += 64) {
            const int rem = end - base;
            const int cnt = rem < 64 ? rem : 64;
            int2 myE = make_int2(0, 0);
            if (lane < cnt) myE = packed[base + lane];
            int j = 0;
            for (; j + 4 <= cnt; j += 4) {
                const int s0 = __builtin_amdgcn_readlane(myE.x, j + 0);
                const int s1 = __builtin_amdgcn_readlane(myE.x, j + 1);
                const int s2 = __builtin_amdgcn_readlane(myE.x, j + 2);
                const int s3 = __builtin_amdgcn_readlane(myE.x, j + 3);
                const float w0 = __uint_as_float(__builtin_amdgcn_readlane(myE.y, j + 0));
                const float w1 = __uint_as_float(__builtin_amdgcn_readlane(myE.y, j + 1));
                const float w2 = __uint_as_float(__builtin_amdgcn_readlane(myE.y, j + 2));
                const float w3 = __uint_as_float(__builtin_amdgcn_readlane(myE.y, j + 3));
                const unsigned v0 = h[(size_t)s0 * 64 + lane];
                const unsigned v1 = h[(size_t)s1 * 64 + lane];
                const unsigned v2 = h[(size_t)s2 * 64 + lane];
                const unsigned v3 = h[(size_t)s3 * 64 + lane];
                acc.x = fmaf(w0, blo(v0), acc.x); acc.y = fmaf(w0, bhi(v0), acc.y);
                acc.x = fmaf(w1, blo(v1), acc.x); acc.y = fmaf(w1, bhi(v1), acc.y);
                acc.x = fmaf(w2, blo(v2), acc.x); acc.y = fmaf(w2, bhi(v2), acc.y);
                acc.x = fmaf(w3, blo(v3), acc.x); acc.y = fmaf(w3, bhi(v3), acc.y);
            }
            for (; j < cnt; ++j) {
                const int s0 = __builtin_amdgcn_readlane(myE.x, j);
                const float w0 = __uint_as_float(__builtin_amdgcn_readlane(myE.y, j));
                const unsigned v0 = h[(size_t)s0 * 64 + lane];
                acc.x = fmaf(w0, blo(v0), acc.x); acc.y = fmaf(w0, bhi(v0), acc.y);
            }
        }
        aggb[(size_t)n * 64 + lane] =
            (unsigned)f2bf(acc.x) | ((unsigned)f2bf(acc.y) << 16);
        csum.x += acc.x; csum.y += acc.y;
        csq.x = fmaf(acc.x, acc.x, csq.x);
        csq.y = fmaf(acc.y, acc.y, csq.y);
    }

    __shared__ float2 lsum[256], lsq[256];
    lsum[tid] = csum; lsq[tid] = csq;
    __syncthreads();
    if (tid < 64) {
        float sx = lsum[tid].x + lsum[64 + tid].x + lsum[128 + tid].x + lsum[192 + tid].x;
        float sy = lsum[tid].y + lsum[64 + tid].y + lsum[128 + tid].y + lsum[192 + tid].y;
        float qx = lsq[tid].x + lsq[64 + tid].x + lsq[128 + tid].x + lsq[192 + tid].x;
        float qy = lsq[tid].y + lsq[64 + tid].y + lsq[128 + tid].y + lsq[192 + tid].y;
        atomicAdd(&sum[2 * tid + 0], sx);
        atomicAdd(&sum[2 * tid + 1], sy);
        atomicAdd(&sq[2 * tid + 0], qx);
        atomicAdd(&sq[2 * tid + 1], qy);
    }
}

// ---------------- collapsed layer 2 ----------------
__global__ __launch_bounds__(256) void wcolsum_bf16(
    const unsigned* __restrict__ xb, const float* __restrict__ cw,
    const float* __restrict__ sum1, const float* __restrict__ sq1,
    const float* __restrict__ g, const float* __restrict__ be,
    float* __restrict__ sout, int N)
{
    __shared__ float Aaf[128], Baf[128];
    __shared__ float2 ls[256];
    const int tid = threadIdx.x;
    if (tid < 128) {
        const float invN = 1.0f / (float)N;
        const float m = sum1[tid] * invN;
        const float var = sq1[tid] * invN - m * m;
        const float rs = rsqrtf(var + BN_EPS);
        Aaf[tid] = g[tid] * rs;
        Baf[tid] = be[tid] - g[tid] * m * rs;
    }
    __syncthreads();
    const int u = tid & 63, rr = tid >> 6;
    const float ax = Aaf[2 * u], ay = Aaf[2 * u + 1];
    const float bx = Baf[2 * u], by = Baf[2 * u + 1];
    float2 s = {0.f, 0.f};
    for (int row = blockIdx.x * 4 + rr; row < N; row += gridDim.x * 4) {
        const unsigned v = xb[(size_t)row * 64 + u];
        const float c = cw[row];
        const float x = fmaxf(fmaf(ax, blo(v), bx), 0.f);
        const float y = fmaxf(fmaf(ay, bhi(v), by), 0.f);
        s.x = fmaf(c, x, s.x);
        s.y = fmaf(c, y, s.y);
    }
    ls[tid] = s;
    __syncthreads();
    if (tid < 64) {
        float sx = ls[tid].x + ls[64 + tid].x + ls[128 + tid].x + ls[192 + tid].x;
        float sy = ls[tid].y + ls[64 + tid].y + ls[128 + tid].y + ls[192 + tid].y;
        atomicAdd(&sout[2 * tid + 0], sx);
        atomicAdd(&sout[2 * tid + 1], sy);
    }
}

__global__ void final_out(
    const float* __restrict__ s, const float* __restrict__ W2,
    const float* __restrict__ b2, float* __restrict__ out, int N, int Dout)
{
    const int j = threadIdx.x;
    if (j < Dout) {
        float acc = 0.f;
        for (int f = 0; f < 128; ++f) acc = fmaf(s[f], W2[f * Dout + j], acc);
        out[j] = acc + (float)N * b2[j];
    }
}

extern "C" void kernel_launch(void* const* d_in, const int* in_sizes, int n_in,
                              void* d_out, int out_size, void* d_ws, size_t ws_size,
                              hipStream_t stream)
{
    const float* nf  = (const float*)d_in[0];
    const int*   ei  = (const int*)d_in[1];
    const float* ew  = (const float*)d_in[2];
    const float* W0  = (const float*)d_in[3];
    // b0 = d_in[4], b1 = d_in[6]: cancel inside BatchNorm, unused
    const float* W1  = (const float*)d_in[5];
    const float* W2  = (const float*)d_in[7];
    const float* b2  = (const float*)d_in[8];
    const float* g0  = (const float*)d_in[9];
    const float* be0 = (const float*)d_in[10];
    const float* g1  = (const float*)d_in[11];
    const float* be1 = (const float*)d_in[12];

    const int N = in_sizes[0] / 128;
    const int E = in_sizes[2];
    const int* srcI = ei;       // edge_index[0,:]
    const int* dstI = ei + E;   // edge_index[1,:]

    const int B = (N + NPB - 1) / NPB;        // 196 for N=100k (must be <= MAXB)
    const int chunk = (E + PB - 1) / PB;

    const size_t HB = ((size_t)N * 128 * 2 + 255) & ~(size_t)255;  // bf16 buf
    const size_t NA = ((size_t)N * sizeof(int) + 255) & ~(size_t)255;
    const size_t CB = (((size_t)B * PB * 4) + 255) & ~(size_t)255; // cursor mtx
    char* ws = (char*)d_ws;
    size_t off = 0;
    float* cw    = (float*)(ws + off); off += NA;
    int*   rp    = (int*)  (ws + off); off += NA;
    float* stats = (float*)(ws + off); off += 4096;
    int*   cntD  = (int*)  (ws + off); off += CB;
    int*   cntS  = (int*)  (ws + off); off += CB;
    int*   baseD = (int*)  (ws + off); off += 2048;
    int*   baseS = (int*)  (ws + off); off += 2048;
    unsigned short* hbuf = (unsigned short*)(ws + off); off += HB;  // h (bf16)
    unsigned* aggb = (unsigned*)(ws + off); off += HB;              // agg (bf16)
    int2*  packed = (int2*)(ws + off); off += (size_t)E * 8;
    uint2* bktD  = (uint2*)(ws + off); off += (size_t)E * 8;
    uint2* bktS  = (uint2*)(ws + off); off += (size_t)E * 8;
    unsigned short* wt0 = (unsigned short*)(ws + off); off += 32768;
    unsigned short* wt1 = (unsigned short*)(ws + off); off += 32768;
    (void)ws_size;  // rounds 1-4 proved ws_size >= 116.5 MB; this needs ~91.5 MB

    float* sum0 = stats + 0;   float* sq0 = stats + 128;
    float* sum1 = stats + 256; float* sq1 = stats + 384;
    float* svec = stats + 512;

    const int gemmGrid = (N + 63) / 64;
    const int aggGrid  = (N + 4 * AGG_R - 1) / (4 * AGG_R);

    hipMemsetAsync(stats, 0, 640 * sizeof(float), stream);

    // ---- atomic-free CSR build + cw (graph identical both layers) ----
    bucket_hist<<<PB, 256, 0, stream>>>(srcI, dstI, cntD, cntS, E, B, chunk);
    bucket_base<<<1, 256, 0, stream>>>(cntD, cntS, baseD, baseS, B, E);
    bucket_cursor<<<2 * B, 256, 0, stream>>>(cntD, cntS, baseD, baseS, B);
    bucket_place<<<PB, 256, 0, stream>>>(srcI, dstI, ew, cntD, cntS, bktD, bktS, E, B, chunk);
    bucket_sort<<<B, 256, 0, stream>>>(bktD, baseD, rp, packed, N);
    bucket_cw<<<B, 256, 0, stream>>>(bktS, baseS, cw, N);
    wconv<<<64, 256, 0, stream>>>(W0, W1, wt0, wt1);

    // ---- layer 0 ----
    gemm0<<<gemmGrid, 256, 0, stream>>>(nf, wt0, hbuf, N);
    aggregate_fused<<<aggGrid, 256, 0, stream>>>(
        packed, rp, (const unsigned*)hbuf, aggb, sum0, sq0, N);

    // ---- layer 1 (BN0+ReLU folded into GEMM staging) ----
    gemm1<<<gemmGrid, 256, 0, stream>>>(aggb, wt1, hbuf, sum0, sq0, g0, be0, N, N);
    aggregate_fused<<<aggGrid, 256, 0, stream>>>(
        packed, rp, (const unsigned*)hbuf, aggb, sum1, sq1, N);

    // ---- collapsed layer 2: out = (sum_n cw[n]*relu(BN1(x2))[n,:]) @ W2 + N*b2 ----
    wcolsum_bf16<<<2048, 256, 0, stream>>>(aggb, cw, sum1, sq1, g1, be1, svec, N);
    final_out<<<1, 64, 0, stream>>>(svec, W2, b2, (float*)d_out, N, out_size);
}

// Round 6
// 573.679 us; speedup vs baseline: 10.6158x; 1.1054x over previous
//
#include <hip/hip_runtime.h>

#define BN_EPS 1e-5f

// Bucket-sort parameters: NPB nodes per bucket (pow2), PB placement blocks.
#define NPB 512
#define NPB_SHIFT 9
#define PB 512
#define MAXB 256

typedef __attribute__((ext_vector_type(8))) short short8;
typedef __attribute__((ext_vector_type(4))) float floatx4;

__device__ __forceinline__ unsigned short f2bf(float f) {
    unsigned u = __float_as_uint(f);
    unsigned r = u + 0x7FFFu + ((u >> 16) & 1u);   // round-to-nearest-even
    return (unsigned short)(r >> 16);
}
__device__ __forceinline__ float blo(unsigned v) { return __uint_as_float(v << 16); }
__device__ __forceinline__ float bhi(unsigned v) { return __uint_as_float(v & 0xffff0000u); }

// ---------------- W pre-transpose: wt[n][k] = bf16(W[k][n]) ----------------
__global__ __launch_bounds__(256) void wconv(
    const float* __restrict__ W0, const float* __restrict__ W1,
    unsigned short* __restrict__ wt0, unsigned short* __restrict__ wt1)
{
    const int idx = blockIdx.x * 256 + threadIdx.x;   // < 16384
    const int n = idx >> 7, k = idx & 127;
    wt0[idx] = f2bf(W0[k * 128 + n]);
    wt1[idx] = f2bf(W1[k * 128 + n]);
}

// ---------------- layer-0 GEMM: C[M x 128] = A_fp32 @ W ----------------
__global__ __launch_bounds__(256) void gemm0(
    const float* __restrict__ A, const unsigned short* __restrict__ Wt,
    unsigned short* __restrict__ C, int M)
{
    __shared__ char lds[53248];
    unsigned short* Al = (unsigned short*)lds;            // [64][136] bf16
    unsigned short* Wl = (unsigned short*)(lds + 17408);  // [128][136] bf16
    float* Cl = (float*)lds;                              // [64][132] f32 (reuse)

    const int tid = threadIdx.x;
    const int r0 = blockIdx.x * 64;

#pragma unroll
    for (int i = 0; i < 16; ++i) {
        const int idx = i * 256 + tid;          // ushort4 units
        const int n = idx >> 5, q = idx & 31;
        const ushort4 v = ((const ushort4*)Wt)[idx];
        *(ushort4*)&Wl[n * 136 + q * 4] = v;
    }
#pragma unroll
    for (int i = 0; i < 8; ++i) {
        const int row = i * 8 + (tid >> 5), q = tid & 31;
        const int gr = r0 + row;
        float4 v = (gr < M) ? ((const float4*)A)[(size_t)gr * 32 + q]
                            : make_float4(0.f, 0.f, 0.f, 0.f);
        ushort4 o;
        o.x = f2bf(v.x); o.y = f2bf(v.y); o.z = f2bf(v.z); o.w = f2bf(v.w);
        *(ushort4*)&Al[row * 136 + q * 4] = o;
    }
    __syncthreads();

    const int wave = tid >> 6, lane = tid & 63;
    const int lrow = lane & 15, quad = lane >> 4;
    const int n0 = wave * 32;

    floatx4 acc[4][2];
#pragma unroll
    for (int mt = 0; mt < 4; ++mt)
#pragma unroll
        for (int t = 0; t < 2; ++t)
#pragma unroll
            for (int j = 0; j < 4; ++j) acc[mt][t][j] = 0.f;

#pragma unroll
    for (int c = 0; c < 4; ++c) {
        const int k0 = c * 32;
        const short8 b0 = *(const short8*)&Wl[(n0 + lrow) * 136 + k0 + quad * 8];
        const short8 b1 = *(const short8*)&Wl[(n0 + 16 + lrow) * 136 + k0 + quad * 8];
#pragma unroll
        for (int mt = 0; mt < 4; ++mt) {
            const short8 a = *(const short8*)&Al[(mt * 16 + lrow) * 136 + k0 + quad * 8];
            acc[mt][0] = __builtin_amdgcn_mfma_f32_16x16x32_bf16(a, b0, acc[mt][0], 0, 0, 0);
            acc[mt][1] = __builtin_amdgcn_mfma_f32_16x16x32_bf16(a, b1, acc[mt][1], 0, 0, 0);
        }
    }
    __syncthreads();

#pragma unroll
    for (int mt = 0; mt < 4; ++mt)
#pragma unroll
        for (int t = 0; t < 2; ++t)
#pragma unroll
            for (int j = 0; j < 4; ++j)
                Cl[(mt * 16 + quad * 4 + j) * 132 + n0 + t * 16 + lrow] = acc[mt][t][j];
    __syncthreads();

#pragma unroll
    for (int i = 0; i < 4; ++i) {
        const int row = i * 16 + (tid >> 4);
        const int c0 = (tid & 15) * 8;
        const int gr = r0 + row;
        if (gr < M) {
            const float4 v0 = *(float4*)&Cl[row * 132 + c0];
            const float4 v1 = *(float4*)&Cl[row * 132 + c0 + 4];
            uint4 o;
            o.x = (unsigned)f2bf(v0.x) | ((unsigned)f2bf(v0.y) << 16);
            o.y = (unsigned)f2bf(v0.z) | ((unsigned)f2bf(v0.w) << 16);
            o.z = (unsigned)f2bf(v1.x) | ((unsigned)f2bf(v1.y) << 16);
            o.w = (unsigned)f2bf(v1.z) | ((unsigned)f2bf(v1.w) << 16);
            ((uint4*)C)[(size_t)gr * 16 + (c0 >> 3)] = o;
        }
    }
}

// ---------------- layer-1 GEMM: C = relu(BN(A_bf16)) @ W ----------------
__global__ __launch_bounds__(256) void gemm1(
    const unsigned* __restrict__ Ab, const unsigned short* __restrict__ Wt,
    unsigned short* __restrict__ C,
    const float* __restrict__ sum, const float* __restrict__ sq,
    const float* __restrict__ g, const float* __restrict__ be,
    int M, int N)
{
    __shared__ char lds[53248];
    unsigned short* Al = (unsigned short*)lds;            // [64][136]
    unsigned short* Wl = (unsigned short*)(lds + 17408);  // [128][136]
    float* AscL = (float*)(lds + 52224);                  // [128]
    float* AshL = AscL + 128;
    float* Cl = (float*)lds;

    const int tid = threadIdx.x;
    const int r0 = blockIdx.x * 64;

    if (tid < 128) {
        const float invN = 1.0f / (float)N;
        const float m = sum[tid] * invN;
        const float var = sq[tid] * invN - m * m;
        const float rs = rsqrtf(var + BN_EPS);
        AscL[tid] = g[tid] * rs;
        AshL[tid] = be[tid] - g[tid] * m * rs;
    }
    __syncthreads();

#pragma unroll
    for (int i = 0; i < 16; ++i) {
        const int idx = i * 256 + tid;
        const int n = idx >> 5, q = idx & 31;
        const ushort4 v = ((const ushort4*)Wt)[idx];
        *(ushort4*)&Wl[n * 136 + q * 4] = v;
    }
#pragma unroll
    for (int i = 0; i < 4; ++i) {
        const int idx = i * 256 + tid;
        const int row = idx >> 4, qc = idx & 15;
        const int gr = r0 + row;
        uint4 v = (gr < M) ? ((const uint4*)Ab)[(size_t)gr * 16 + qc]
                           : make_uint4(0, 0, 0, 0);
        const float4 a0 = *(const float4*)&AscL[qc * 8];
        const float4 a1 = *(const float4*)&AscL[qc * 8 + 4];
        const float4 b0 = *(const float4*)&AshL[qc * 8];
        const float4 b1 = *(const float4*)&AshL[qc * 8 + 4];
        float x0 = fmaxf(fmaf(a0.x, blo(v.x), b0.x), 0.f);
        float x1 = fmaxf(fmaf(a0.y, bhi(v.x), b0.y), 0.f);
        float x2 = fmaxf(fmaf(a0.z, blo(v.y), b0.z), 0.f);
        float x3 = fmaxf(fmaf(a0.w, bhi(v.y), b0.w), 0.f);
        float x4 = fmaxf(fmaf(a1.x, blo(v.z), b1.x), 0.f);
        float x5 = fmaxf(fmaf(a1.y, bhi(v.z), b1.y), 0.f);
        float x6 = fmaxf(fmaf(a1.z, blo(v.w), b1.z), 0.f);
        float x7 = fmaxf(fmaf(a1.w, bhi(v.w), b1.w), 0.f);
        uint4 o;
        o.x = (unsigned)f2bf(x0) | ((unsigned)f2bf(x1) << 16);
        o.y = (unsigned)f2bf(x2) | ((unsigned)f2bf(x3) << 16);
        o.z = (unsigned)f2bf(x4) | ((unsigned)f2bf(x5) << 16);
        o.w = (unsigned)f2bf(x6) | ((unsigned)f2bf(x7) << 16);
        *(uint4*)&Al[row * 136 + qc * 8] = o;
    }
    __syncthreads();

    const int wave = tid >> 6, lane = tid & 63;
    const int lrow = lane & 15, quad = lane >> 4;
    const int n0 = wave * 32;

    floatx4 acc[4][2];
#pragma unroll
    for (int mt = 0; mt < 4; ++mt)
#pragma unroll
        for (int t = 0; t < 2; ++t)
#pragma unroll
            for (int j = 0; j < 4; ++j) acc[mt][t][j] = 0.f;

#pragma unroll
    for (int c = 0; c < 4; ++c) {
        const int k0 = c * 32;
        const short8 b0 = *(const short8*)&Wl[(n0 + lrow) * 136 + k0 + quad * 8];
        const short8 b1 = *(const short8*)&Wl[(n0 + 16 + lrow) * 136 + k0 + quad * 8];
#pragma unroll
        for (int mt = 0; mt < 4; ++mt) {
            const short8 a = *(const short8*)&Al[(mt * 16 + lrow) * 136 + k0 + quad * 8];
            acc[mt][0] = __builtin_amdgcn_mfma_f32_16x16x32_bf16(a, b0, acc[mt][0], 0, 0, 0);
            acc[mt][1] = __builtin_amdgcn_mfma_f32_16x16x32_bf16(a, b1, acc[mt][1], 0, 0, 0);
        }
    }
    __syncthreads();

#pragma unroll
    for (int mt = 0; mt < 4; ++mt)
#pragma unroll
        for (int t = 0; t < 2; ++t)
#pragma unroll
            for (int j = 0; j < 4; ++j)
                Cl[(mt * 16 + quad * 4 + j) * 132 + n0 + t * 16 + lrow] = acc[mt][t][j];
    __syncthreads();

#pragma unroll
    for (int i = 0; i < 4; ++i) {
        const int row = i * 16 + (tid >> 4);
        const int c0 = (tid & 15) * 8;
        const int gr = r0 + row;
        if (gr < M) {
            const float4 v0 = *(float4*)&Cl[row * 132 + c0];
            const float4 v1 = *(float4*)&Cl[row * 132 + c0 + 4];
            uint4 o;
            o.x = (unsigned)f2bf(v0.x) | ((unsigned)f2bf(v0.y) << 16);
            o.y = (unsigned)f2bf(v0.z) | ((unsigned)f2bf(v0.w) << 16);
            o.z = (unsigned)f2bf(v1.x) | ((unsigned)f2bf(v1.y) << 16);
            o.w = (unsigned)f2bf(v1.z) | ((unsigned)f2bf(v1.w) << 16);
            ((uint4*)C)[(size_t)gr * 16 + (c0 >> 3)] = o;
        }
    }
}

// ============ atomic-free CSR build: two-level bucket counting sort ============

__global__ __launch_bounds__(256) void bucket_hist(
    const int* __restrict__ src, const int* __restrict__ dst,
    int* __restrict__ cntD, int* __restrict__ cntS, int E, int B, int chunk)
{
    __shared__ int hD[MAXB], hS[MAXB];
    const int tid = threadIdx.x;
    for (int i = tid; i < B; i += 256) { hD[i] = 0; hS[i] = 0; }
    __syncthreads();
    const int lo = blockIdx.x * chunk;
    const int hi = min(E, lo + chunk);
    for (int e = lo + tid; e < hi; e += 256) {
        atomicAdd(&hD[dst[e] >> NPB_SHIFT], 1);
        atomicAdd(&hS[src[e] >> NPB_SHIFT], 1);
    }
    __syncthreads();
    for (int i = tid; i < B; i += 256) {
        cntD[i * PB + blockIdx.x] = hD[i];
        cntS[i * PB + blockIdx.x] = hS[i];
    }
}

__global__ __launch_bounds__(256) void bucket_base(
    const int* __restrict__ cntD, const int* __restrict__ cntS,
    int* __restrict__ baseD, int* __restrict__ baseS, int B, int E)
{
    __shared__ int lD[256], lS[256];
    const int tid = threadIdx.x;
    int sD = 0, sS = 0;
    if (tid < B) {
        const int4* pD = (const int4*)(cntD + tid * PB);
        const int4* pS = (const int4*)(cntS + tid * PB);
        for (int j = 0; j < PB / 4; ++j) {
            const int4 a = pD[j], b = pS[j];
            sD += a.x + a.y + a.z + a.w;
            sS += b.x + b.y + b.z + b.w;
        }
    }
    lD[tid] = sD; lS[tid] = sS;
    __syncthreads();
    for (int st = 1; st < 256; st <<= 1) {
        const int vD = (tid >= st) ? lD[tid - st] : 0;
        const int vS = (tid >= st) ? lS[tid - st] : 0;
        __syncthreads();
        lD[tid] += vD; lS[tid] += vS;
        __syncthreads();
    }
    if (tid < B) { baseD[tid] = lD[tid] - sD; baseS[tid] = lS[tid] - sS; }
    if (tid == 0) { baseD[B] = E; baseS[B] = E; }
}

__global__ __launch_bounds__(256) void bucket_cursor(
    int* __restrict__ cntD, int* __restrict__ cntS,
    const int* __restrict__ baseD, const int* __restrict__ baseS, int B)
{
    int b = blockIdx.x;
    int* cnt; const int* base;
    if (b < B) { cnt = cntD; base = baseD; }
    else       { cnt = cntS; base = baseS; b -= B; }
    __shared__ int ls[256];
    const int tid = threadIdx.x;
    const int c0 = cnt[b * PB + 2 * tid];
    const int c1 = cnt[b * PB + 2 * tid + 1];
    const int s = c0 + c1;
    ls[tid] = s;
    __syncthreads();
    for (int st = 1; st < 256; st <<= 1) {
        const int v = (tid >= st) ? ls[tid - st] : 0;
        __syncthreads();
        ls[tid] += v;
        __syncthreads();
    }
    const int excl = ls[tid] - s + base[b];
    cnt[b * PB + 2 * tid] = excl;
    cnt[b * PB + 2 * tid + 1] = excl + c0;
}

__global__ __launch_bounds__(256) void bucket_place(
    const int* __restrict__ src, const int* __restrict__ dst,
    const float* __restrict__ ew,
    const int* __restrict__ curD, const int* __restrict__ curS,
    uint2* __restrict__ bktD, uint2* __restrict__ bktS, int E, int B, int chunk)
{
    __shared__ int cD[MAXB], cS[MAXB];
    const int tid = threadIdx.x;
    for (int i = tid; i < B; i += 256) {
        cD[i] = curD[i * PB + blockIdx.x];
        cS[i] = curS[i * PB + blockIdx.x];
    }
    __syncthreads();
    const int lo = blockIdx.x * chunk;
    const int hi = min(E, lo + chunk);
    for (int e = lo + tid; e < hi; e += 256) {
        const int s = src[e], d = dst[e];
        const unsigned wb = __float_as_uint(ew[e]);
        const int pd = atomicAdd(&cD[d >> NPB_SHIFT], 1);
        bktD[pd] = make_uint2(((unsigned)s << NPB_SHIFT) | (unsigned)(d & (NPB - 1)), wb);
        const int ps = atomicAdd(&cS[s >> NPB_SHIFT], 1);
        bktS[ps] = make_uint2((unsigned)(s & (NPB - 1)), wb);
    }
}

__global__ __launch_bounds__(256) void bucket_sort(
    const uint2* __restrict__ bktD, const int* __restrict__ baseD,
    int* __restrict__ rp, int2* __restrict__ packed, int N)
{
    const int b = blockIdx.x;
    const int lo = baseD[b], hi = baseD[b + 1];
    __shared__ int cnt[NPB], cur[NPB];
    __shared__ int ls[256];
    const int tid = threadIdx.x;
    cnt[2 * tid] = 0; cnt[2 * tid + 1] = 0;
    __syncthreads();
    for (int i = lo + tid; i < hi; i += 256)
        atomicAdd(&cnt[bktD[i].x & (NPB - 1)], 1);
    __syncthreads();
    const int c0 = cnt[2 * tid], c1 = cnt[2 * tid + 1];
    const int s = c0 + c1;
    ls[tid] = s;
    __syncthreads();
    for (int st = 1; st < 256; st <<= 1) {
        const int v = (tid >= st) ? ls[tid - st] : 0;
        __syncthreads();
        ls[tid] += v;
        __syncthreads();
    }
    const int excl = ls[tid] - s;
    const int n0 = b * NPB + 2 * tid;
    if (n0 < N)     rp[n0]     = lo + excl + c0;
    if (n0 + 1 < N) rp[n0 + 1] = lo + excl + c0 + c1;
    cur[2 * tid]     = lo + excl;
    cur[2 * tid + 1] = lo + excl + c0;
    __syncthreads();
    for (int i = lo + tid; i < hi; i += 256) {
        const uint2 r = bktD[i];
        const int pos = atomicAdd(&cur[r.x & (NPB - 1)], 1);
        packed[pos] = make_int2((int)(r.x >> NPB_SHIFT), (int)r.y);
    }
}

__global__ __launch_bounds__(256) void bucket_cw(
    const uint2* __restrict__ bktS, const int* __restrict__ baseS,
    float* __restrict__ cw, int N)
{
    const int b = blockIdx.x;
    const int lo = baseS[b], hi = baseS[b + 1];
    __shared__ float sm[NPB];
    const int tid = threadIdx.x;
    sm[2 * tid] = 0.f; sm[2 * tid + 1] = 0.f;
    __syncthreads();
    for (int i = lo + tid; i < hi; i += 256) {
        const uint2 r = bktS[i];
        atomicAdd(&sm[r.x], __uint_as_float(r.y));
    }
    __syncthreads();
    const int n0 = b * NPB + 2 * tid;
    if (n0 < N)     cw[n0]     = sm[2 * tid];
    if (n0 + 1 < N) cw[n0 + 1] = sm[2 * tid + 1];
}

// ---------------- fused aggregate + BN stats (v4: quarter-wave gathers) ----
// Each edge handled by a 16-lane quarter-wave reading uint4 (16 B/lane ->
// 1 KiB/instruction); 4 edges in flight per j-group. Butterfly reduce across
// quarters, lane<16 writes a coalesced uint4 row segment.
#define AGG_R 16
__global__ __launch_bounds__(256) void aggregate4(
    const int2* __restrict__ packed, const int* __restrict__ rp,
    const uint4* __restrict__ h4, uint4* __restrict__ aggb4,
    float* __restrict__ sum, float* __restrict__ sq, int N)
{
    const int tid = threadIdx.x;
    const int lane = tid & 63, wave = tid >> 6;
    const int sub = lane >> 4;          // quarter 0..3 -> edge j+sub
    const int u = lane & 15;            // cols 8u..8u+7 (uint4)
    const int n0 = (blockIdx.x * 4 + wave) * AGG_R;

    float csum[8], csq[8];
#pragma unroll
    for (int k = 0; k < 8; ++k) { csum[k] = 0.f; csq[k] = 0.f; }

    for (int r = 0; r < AGG_R; ++r) {
        const int n = n0 + r;
        if (n >= N) break;
        const int start = __builtin_amdgcn_readfirstlane((n == 0) ? 0 : rp[n - 1]);
        const int end   = __builtin_amdgcn_readfirstlane(rp[n]);
        float a[8];
#pragma unroll
        for (int k = 0; k < 8; ++k) a[k] = 0.f;

        for (int base = start; base < end; base += 64) {
            const int cnt = min(64, end - base);
            int2 myE = make_int2(0, 0);
            if (lane < cnt) myE = packed[base + lane];
            for (int j = 0; j < cnt; j += 16) {
                const int i0 = j + sub, i1 = i0 + 4, i2 = i0 + 8, i3 = i0 + 12;
                const int c0 = (i0 < cnt) ? i0 : 0;
                const int c1 = (i1 < cnt) ? i1 : 0;
                const int c2 = (i2 < cnt) ? i2 : 0;
                const int c3 = (i3 < cnt) ? i3 : 0;
                const int s0 = __shfl(myE.x, c0, 64);
                const int s1 = __shfl(myE.x, c1, 64);
                const int s2 = __shfl(myE.x, c2, 64);
                const int s3 = __shfl(myE.x, c3, 64);
                float w0 = __uint_as_float((unsigned)__shfl(myE.y, c0, 64));
                float w1 = __uint_as_float((unsigned)__shfl(myE.y, c1, 64));
                float w2 = __uint_as_float((unsigned)__shfl(myE.y, c2, 64));
                float w3 = __uint_as_float((unsigned)__shfl(myE.y, c3, 64));
                if (i0 >= cnt) w0 = 0.f;
                if (i1 >= cnt) w1 = 0.f;
                if (i2 >= cnt) w2 = 0.f;
                if (i3 >= cnt) w3 = 0.f;
                const uint4 v0 = h4[(size_t)s0 * 16 + u];
                const uint4 v1 = h4[(size_t)s1 * 16 + u];
                const uint4 v2 = h4[(size_t)s2 * 16 + u];
                const uint4 v3 = h4[(size_t)s3 * 16 + u];
                a[0] = fmaf(w0, blo(v0.x), a[0]); a[1] = fmaf(w0, bhi(v0.x), a[1]);
                a[2] = fmaf(w0, blo(v0.y), a[2]); a[3] = fmaf(w0, bhi(v0.y), a[3]);
                a[4] = fmaf(w0, blo(v0.z), a[4]); a[5] = fmaf(w0, bhi(v0.z), a[5]);
                a[6] = fmaf(w0, blo(v0.w), a[6]); a[7] = fmaf(w0, bhi(v0.w), a[7]);
                a[0] = fmaf(w1, blo(v1.x), a[0]); a[1] = fmaf(w1, bhi(v1.x), a[1]);
                a[2] = fmaf(w1, blo(v1.y), a[2]); a[3] = fmaf(w1, bhi(v1.y), a[3]);
                a[4] = fmaf(w1, blo(v1.z), a[4]); a[5] = fmaf(w1, bhi(v1.z), a[5]);
                a[6] = fmaf(w1, blo(v1.w), a[6]); a[7] = fmaf(w1, bhi(v1.w), a[7]);
                a[0] = fmaf(w2, blo(v2.x), a[0]); a[1] = fmaf(w2, bhi(v2.x), a[1]);
                a[2] = fmaf(w2, blo(v2.y), a[2]); a[3] = fmaf(w2, bhi(v2.y), a[3]);
                a[4] = fmaf(w2, blo(v2.z), a[4]); a[5] = fmaf(w2, bhi(v2.z), a[5]);
                a[6] = fmaf(w2, blo(v2.w), a[6]); a[7] = fmaf(w2, bhi(v2.w), a[7]);
                a[0] = fmaf(w3, blo(v3.x), a[0]); a[1] = fmaf(w3, bhi(v3.x), a[1]);
                a[2] = fmaf(w3, blo(v3.y), a[2]); a[3] = fmaf(w3, bhi(v3.y), a[3]);
                a[4] = fmaf(w3, blo(v3.z), a[4]); a[5] = fmaf(w3, bhi(v3.z), a[5]);
                a[6] = fmaf(w3, blo(v3.w), a[6]); a[7] = fmaf(w3, bhi(v3.w), a[7]);
            }
        }
        // reduce across the 4 quarter-waves
#pragma unroll
        for (int k = 0; k < 8; ++k) {
            a[k] += __shfl_xor(a[k], 16, 64);
            a[k] += __shfl_xor(a[k], 32, 64);
        }
        if (sub == 0) {
            uint4 o;
            o.x = (unsigned)f2bf(a[0]) | ((unsigned)f2bf(a[1]) << 16);
            o.y = (unsigned)f2bf(a[2]) | ((unsigned)f2bf(a[3]) << 16);
            o.z = (unsigned)f2bf(a[4]) | ((unsigned)f2bf(a[5]) << 16);
            o.w = (unsigned)f2bf(a[6]) | ((unsigned)f2bf(a[7]) << 16);
            aggb4[(size_t)n * 16 + u] = o;
#pragma unroll
            for (int k = 0; k < 8; ++k) {
                csum[k] += a[k];
                csq[k] = fmaf(a[k], a[k], csq[k]);
            }
        }
    }

    __shared__ float lsum[512], lsq[512];   // [wave][col=u*8+k]
    if (sub == 0) {
#pragma unroll
        for (int k = 0; k < 8; ++k) {
            lsum[wave * 128 + u * 8 + k] = csum[k];
            lsq[wave * 128 + u * 8 + k] = csq[k];
        }
    }
    __syncthreads();
    if (tid < 128) {
        const float s = lsum[tid] + lsum[128 + tid] + lsum[256 + tid] + lsum[384 + tid];
        const float q = lsq[tid] + lsq[128 + tid] + lsq[256 + tid] + lsq[384 + tid];
        atomicAdd(&sum[tid], s);
        atomicAdd(&sq[tid], q);
    }
}

// ---------------- collapsed layer 2 ----------------
__global__ __launch_bounds__(256) void wcolsum_bf16(
    const unsigned* __restrict__ xb, const float* __restrict__ cw,
    const float* __restrict__ sum1, const float* __restrict__ sq1,
    const float* __restrict__ g, const float* __restrict__ be,
    float* __restrict__ sout, int N)
{
    __shared__ float Aaf[128], Baf[128];
    __shared__ float2 ls[256];
    const int tid = threadIdx.x;
    if (tid < 128) {
        const float invN = 1.0f / (float)N;
        const float m = sum1[tid] * invN;
        const float var = sq1[tid] * invN - m * m;
        const float rs = rsqrtf(var + BN_EPS);
        Aaf[tid] = g[tid] * rs;
        Baf[tid] = be[tid] - g[tid] * m * rs;
    }
    __syncthreads();
    const int u = tid & 63, rr = tid >> 6;
    const float ax = Aaf[2 * u], ay = Aaf[2 * u + 1];
    const float bx = Baf[2 * u], by = Baf[2 * u + 1];
    float2 s = {0.f, 0.f};
    for (int row = blockIdx.x * 4 + rr; row < N; row += gridDim.x * 4) {
        const unsigned v = xb[(size_t)row * 64 + u];
        const float c = cw[row];
        const float x = fmaxf(fmaf(ax, blo(v), bx), 0.f);
        const float y = fmaxf(fmaf(ay, bhi(v), by), 0.f);
        s.x = fmaf(c, x, s.x);
        s.y = fmaf(c, y, s.y);
    }
    ls[tid] = s;
    __syncthreads();
    if (tid < 64) {
        float sx = ls[tid].x + ls[64 + tid].x + ls[128 + tid].x + ls[192 + tid].x;
        float sy = ls[tid].y + ls[64 + tid].y + ls[128 + tid].y + ls[192 + tid].y;
        atomicAdd(&sout[2 * tid + 0], sx);
        atomicAdd(&sout[2 * tid + 1], sy);
    }
}

__global__ void final_out(
    const float* __restrict__ s, const float* __restrict__ W2,
    const float* __restrict__ b2, float* __restrict__ out, int N, int Dout)
{
    const int j = threadIdx.x;
    if (j < Dout) {
        float acc = 0.f;
        for (int f = 0; f < 128; ++f) acc = fmaf(s[f], W2[f * Dout + j], acc);
        out[j] = acc + (float)N * b2[j];
    }
}

extern "C" void kernel_launch(void* const* d_in, const int* in_sizes, int n_in,
                              void* d_out, int out_size, void* d_ws, size_t ws_size,
                              hipStream_t stream)
{
    const float* nf  = (const float*)d_in[0];
    const int*   ei  = (const int*)d_in[1];
    const float* ew  = (const float*)d_in[2];
    const float* W0  = (const float*)d_in[3];
    // b0 = d_in[4], b1 = d_in[6]: cancel inside BatchNorm, unused
    const float* W1  = (const float*)d_in[5];
    const float* W2  = (const float*)d_in[7];
    const float* b2  = (const float*)d_in[8];
    const float* g0  = (const float*)d_in[9];
    const float* be0 = (const float*)d_in[10];
    const float* g1  = (const float*)d_in[11];
    const float* be1 = (const float*)d_in[12];

    const int N = in_sizes[0] / 128;
    const int E = in_sizes[2];
    const int* srcI = ei;       // edge_index[0,:]
    const int* dstI = ei + E;   // edge_index[1,:]

    const int B = (N + NPB - 1) / NPB;        // 196 for N=100k
    const int chunk = (E + PB - 1) / PB;

    const size_t HB = ((size_t)N * 128 * 2 + 255) & ~(size_t)255;  // bf16 buf
    const size_t NA = ((size_t)N * sizeof(int) + 255) & ~(size_t)255;
    const size_t CB = (((size_t)B * PB * 4) + 255) & ~(size_t)255;
    char* ws = (char*)d_ws;
    size_t off = 0;
    float* cw    = (float*)(ws + off); off += NA;
    int*   rp    = (int*)  (ws + off); off += NA;
    float* stats = (float*)(ws + off); off += 4096;
    int*   cntD  = (int*)  (ws + off); off += CB;
    int*   cntS  = (int*)  (ws + off); off += CB;
    int*   baseD = (int*)  (ws + off); off += 2048;
    int*   baseS = (int*)  (ws + off); off += 2048;
    unsigned short* hbuf = (unsigned short*)(ws + off); off += HB;  // h (bf16)
    unsigned* aggb = (unsigned*)(ws + off); off += HB;              // agg (bf16)
    int2*  packed = (int2*)(ws + off); off += (size_t)E * 8;
    uint2* bktD  = (uint2*)(ws + off); off += (size_t)E * 8;
    uint2* bktS  = (uint2*)(ws + off); off += (size_t)E * 8;
    unsigned short* wt0 = (unsigned short*)(ws + off); off += 32768;
    unsigned short* wt1 = (unsigned short*)(ws + off); off += 32768;
    (void)ws_size;  // rounds 1-5 proved ws_size >= 116.5 MB; this needs ~91.5 MB

    float* sum0 = stats + 0;   float* sq0 = stats + 128;
    float* sum1 = stats + 256; float* sq1 = stats + 384;
    float* svec = stats + 512;

    const int gemmGrid = (N + 63) / 64;
    const int aggGrid  = (N + 4 * AGG_R - 1) / (4 * AGG_R);

    hipMemsetAsync(stats, 0, 640 * sizeof(float), stream);

    // ---- atomic-free CSR build + cw (graph identical both layers) ----
    bucket_hist<<<PB, 256, 0, stream>>>(srcI, dstI, cntD, cntS, E, B, chunk);
    bucket_base<<<1, 256, 0, stream>>>(cntD, cntS, baseD, baseS, B, E);
    bucket_cursor<<<2 * B, 256, 0, stream>>>(cntD, cntS, baseD, baseS, B);
    bucket_place<<<PB, 256, 0, stream>>>(srcI, dstI, ew, cntD, cntS, bktD, bktS, E, B, chunk);
    bucket_sort<<<B, 256, 0, stream>>>(bktD, baseD, rp, packed, N);
    bucket_cw<<<B, 256, 0, stream>>>(bktS, baseS, cw, N);
    wconv<<<64, 256, 0, stream>>>(W0, W1, wt0, wt1);

    // ---- layer 0 ----
    gemm0<<<gemmGrid, 256, 0, stream>>>(nf, wt0, hbuf, N);
    aggregate4<<<aggGrid, 256, 0, stream>>>(
        packed, rp, (const uint4*)hbuf, (uint4*)aggb, sum0, sq0, N);

    // ---- layer 1 (BN0+ReLU folded into GEMM staging) ----
    gemm1<<<gemmGrid, 256, 0, stream>>>(aggb, wt1, hbuf, sum0, sq0, g0, be0, N, N);
    aggregate4<<<aggGrid, 256, 0, stream>>>(
        packed, rp, (const uint4*)hbuf, (uint4*)aggb, sum1, sq1, N);

    // ---- collapsed layer 2: out = (sum_n cw[n]*relu(BN1(x2))[n,:]) @ W2 + N*b2 ----
    wcolsum_bf16<<<2048, 256, 0, stream>>>(aggb, cw, sum1, sq1, g1, be1, svec, N);
    final_out<<<1, 64, 0, stream>>>(svec, W2, b2, (float*)d_out, N, out_size);
}